// Round 8
// baseline (1077.100 us; speedup 1.0000x reference)
//
#include <hip/hip_runtime.h>

typedef unsigned short u16;
typedef unsigned int u32;
typedef __bf16 bf16x8 __attribute__((ext_vector_type(8)));
typedef float f32x4 __attribute__((ext_vector_type(4)));
typedef unsigned int u32x4 __attribute__((ext_vector_type(4)));

#define BB 16
#define CC 768
#define PP 2048
#define FF 3072

__device__ __forceinline__ float b2f(u16 u) {
  unsigned int x = ((unsigned int)u) << 16;
  return __builtin_bit_cast(float, x);
}
__device__ __forceinline__ u16 f2b(float f) {
  unsigned int x = __builtin_bit_cast(unsigned int, f);
  x += 0x7fffu + ((x >> 16) & 1u);
  return (u16)(x >> 16);
}
// erf via Abramowitz-Stegun 7.1.26 (|err|<=1.5e-7; invisible after bf16 round)
__device__ __forceinline__ float erf_fast(float x) {
  float ax = fabsf(x);
  float t = 1.0f / fmaf(0.3275911f, ax, 1.0f);
  float p = t * fmaf(t, fmaf(t, fmaf(t, fmaf(t, 1.061405429f, -1.453152027f),
                                     1.421413741f), -0.284496736f), 0.254829592f);
  float r = 1.0f - p * __expf(-ax * ax);
  return copysignf(r, x);
}
__device__ __forceinline__ float gelu_f(float x) {
  return 0.5f * x * (1.0f + erf_fast(x * 0.7071067811865475f));
}

typedef __attribute__((address_space(1))) const unsigned int g_u32;
typedef __attribute__((address_space(3))) unsigned int l_u32;
__device__ __forceinline__ void gl_lds16(const u16* g, u16* l) {
  __builtin_amdgcn_global_load_lds((g_u32*)g, (l_u32*)l, 16, 0, 0);
}

// --------- fused weight prep: tr: Wt[n,k]=g[k]W[k,n] | copy: Wt[k,n]=g[k]W[k,n]
struct Wtr10 {
  const float* W[10]; const float* g[10]; u16* O[10];
  int Kd[10]; int Nd[10]; int tr[10]; int cum[11];
};
__global__ void wtr10_k(Wtr10 a) {
  __shared__ float t[64][65];
  int tbid = blockIdx.x;
  int z = 0;
  while (tbid >= a.cum[z + 1]) ++z;
  int r = tbid - a.cum[z];
  const float* W = a.W[z];
  const float* g = a.g[z];
  u16* Wt = a.O[z];
  int K = a.Kd[z], N = a.Nd[z];
  int nbx = N >> 6;
  int n0 = (r % nbx) * 64, k0 = (r / nbx) * 64;
  int tx = threadIdx.x & 63, ty = threadIdx.x >> 6;
  if (!a.tr[z]) {  // scaled copy, row-major [K][N]
    for (int i = 0; i < 16; ++i) {
      int k = k0 + ty + i * 4;
      float sc = g ? g[k] : 1.0f;
      Wt[(long)k * N + n0 + tx] = f2b(W[(long)k * N + n0 + tx] * sc);
    }
    return;
  }
  for (int i = 0; i < 16; ++i) {
    int k = k0 + ty + i * 4;
    float sc = g ? g[k] : 1.0f;
    t[ty + i * 4][tx] = W[(long)k * N + n0 + tx] * sc;
  }
  __syncthreads();
  for (int i = 0; i < 16; ++i) {
    int n = n0 + ty + i * 4;
    Wt[(long)n * K + k0 + tx] = f2b(t[tx][ty + i * 4]);
  }
}

// fused bias prep: b'[n] = b[n] + sum_k nb[k]*W[k,n]
struct Bf7 {
  const float* b[7]; const float* nb[7]; const float* W[7]; float* o[7];
  int Kd[7]; int Nd[7];
};
__global__ void bfuse7_k(Bf7 a) {
  __shared__ float red[4][64];
  int tbid = blockIdx.x;
  int z, bx;
  if (tbid < 72) { z = tbid / 12; bx = tbid % 12; }
  else { z = 6; bx = tbid - 72; }
  const float* b = a.b[z];
  const float* nb = a.nb[z];
  const float* W = a.W[z];
  float* outb = a.o[z];
  int K = a.Kd[z], N = a.Nd[z];
  int n = bx * 64 + (threadIdx.x & 63);
  int slice = threadIdx.x >> 6;
  float acc = 0.f;
#pragma unroll 4
  for (int k = slice; k < K; k += 4) acc += nb[k] * W[(long)k * N + n];
  red[slice][threadIdx.x & 63] = acc;
  __syncthreads();
  if (slice == 0)
    outb[n] = b[n] + red[0][threadIdx.x & 63] + red[1][threadIdx.x & 63] +
              red[2][threadIdx.x & 63] + red[3][threadIdx.x & 63];
}

// 2 batched bias fuses over [768][768] f32 weights: o[n] = b?[n] + nb.W[:,n]
struct Bf2 { const float* b[2]; const float* nb[2]; const float* W[2]; float* o[2]; };
__global__ void bfuse2_k(Bf2 a) {
  __shared__ float red[4][64];
  int z = blockIdx.x / 12, bx = blockIdx.x % 12;
  const float* b = a.b[z];
  const float* nb = a.nb[z];
  const float* W = a.W[z];
  int n = bx * 64 + (threadIdx.x & 63);
  int slice = threadIdx.x >> 6;
  float acc = 0.f;
#pragma unroll 4
  for (int k = slice; k < CC; k += 4) acc += nb[k] * W[(long)k * CC + n];
  red[slice][threadIdx.x & 63] = acc;
  __syncthreads();
  if (slice == 0)
    a.o[z][n] = (b ? b[n] : 0.f) + red[0][threadIdx.x & 63] +
                red[1][threadIdx.x & 63] + red[2][threadIdx.x & 63] +
                red[3][threadIdx.x & 63];
}

// 4 batched weight-row dots: o[r] = bf16 A[r,:] . vec  (768 rows each)
struct Dw4 { const u16* A[4]; const float* v[4]; float* o[4]; };
__global__ void dotw4_k(Dw4 a) {
  int z = blockIdx.x / 192;
  int row = (blockIdx.x % 192) * 4 + (threadIdx.x >> 6);
  int lane = threadIdx.x & 63;
  const u16* ip = a.A[z] + (long)row * CC;
  const float* vec = a.v[z];
  float s = 0.f;
  for (int i = 0; i < 12; ++i) s += b2f(ip[lane + i * 64]) * vec[lane + i * 64];
  for (int o = 32; o; o >>= 1) s += __shfl_xor(s, o);
  if (lane == 0) a.o[z][row] = s;
}

// two f32 dot-768 scalars
__global__ void scal2_k(const float* a0, const float* b0, float* o0,
                        const float* a1, const float* b1, float* o1) {
  int w = threadIdx.x >> 6, lane = threadIdx.x & 63;
  const float* A = w ? a1 : a0;
  const float* Bv = w ? b1 : b0;
  float s = 0.f;
  for (int i = lane; i < CC; i += 64) s += A[i] * Bv[i];
  for (int o = 32; o; o >>= 1) s += __shfl_xor(s, o);
  if (lane == 0) *(w ? o1 : o0) = s;
}

// out[r] = bf16 A[r,:768] . vec + *cptr   (1024 rows)
__global__ void dotc_k(const u16* __restrict__ A, const float* __restrict__ vec,
                       const float* __restrict__ cptr, float* __restrict__ outp) {
  int row = blockIdx.x * 4 + (threadIdx.x >> 6);
  int lane = threadIdx.x & 63;
  const u16* ip = A + (long)row * CC;
  float s = 0.f;
  for (int i = 0; i < 12; ++i) s += b2f(ip[lane + i * 64]) * vec[lane + i * 64];
  for (int o = 32; o; o >>= 1) s += __shfl_xor(s, o);
  if (lane == 0) outp[row] = s + cptr[0];
}

// ------- fused x prep: stats over C + transposed xhat -------
__global__ void xprep_k(const float* __restrict__ x, float* __restrict__ mean,
                        float* __restrict__ rstd, u16* __restrict__ xh) {
  __shared__ float t[64][65];
  __shared__ float red[8][64];
  __shared__ float mn_s[64], rs_s[64];
  int p0 = blockIdx.x * 64, b = blockIdx.y;
  int tx = threadIdx.x & 63, ty = threadIdx.x >> 6;
  const float* xb = x + (long)b * CC * PP;
  float s = 0.f, sq = 0.f;
  for (int c = ty; c < CC; c += 4) {
    float f = xb[(long)c * PP + p0 + tx];
    s += f; sq += f * f;
  }
  red[ty][tx] = s;
  red[4 + ty][tx] = sq;
  __syncthreads();
  if (ty == 0) {
    float S = red[0][tx] + red[1][tx] + red[2][tx] + red[3][tx];
    float Q = red[4][tx] + red[5][tx] + red[6][tx] + red[7][tx];
    float m = S * (1.0f / 768.0f);
    float var = Q * (1.0f / 768.0f) - m * m;
    float rs = rsqrtf(var + 1e-5f);
    mn_s[tx] = m; rs_s[tx] = rs;
    int gi = (b << 11) + p0 + tx;
    mean[gi] = m; rstd[gi] = rs;
  }
  __syncthreads();
  u16* ob = xh + (long)b * PP * CC;
  for (int cb = 0; cb < 12; ++cb) {
    int c0 = cb * 64;
    for (int i = 0; i < 16; ++i)
      t[ty + i * 4][tx] = xb[(long)(c0 + ty + i * 4) * PP + p0 + tx];
    __syncthreads();
    for (int i = 0; i < 16; ++i) {
      int pl = ty + i * 4;
      ob[(long)(p0 + pl) * CC + c0 + tx] = f2b((t[tx][pl] - mn_s[pl]) * rs_s[pl]);
    }
    __syncthreads();
  }
}

// ---------------- SimpleReasoning gate (compute only) ----------------
__global__ void parts_gate_k(const float* __restrict__ parts,
                             const float* __restrict__ w1, const float* __restrict__ b1,
                             const float* __restrict__ w2, const float* __restrict__ b2,
                             float* __restrict__ gate_out) {
  int b = blockIdx.x, t = threadIdx.x;
  __shared__ float g[64], g1[64];
  int r = t >> 2, l4 = t & 3;
  const float* pr = parts + ((long)b * 64 + r) * CC;
  float m = -1e30f;
  for (int c = l4; c < CC; c += 4) m = fmaxf(m, pr[c]);
  m = fmaxf(m, __shfl_xor(m, 1));
  m = fmaxf(m, __shfl_xor(m, 2));
  if (l4 == 0) g[r] = m;
  __syncthreads();
  if (t < 64) {
    float a = b1[t];
    for (int k = 0; k < 64; ++k) a += g[k] * w1[k * 64 + t];
    g1[t] = gelu_f(a);
  }
  __syncthreads();
  if (t < 64) {
    float a = b2[t];
    for (int k = 0; k < 64; ++k) a += g1[k] * w2[k * 64 + t];
    gate_out[b * 64 + t] = 1.0f / (1.0f + expf(-a));
  }
}

// gate-apply + parts1 write + LN -> p1hat, one pass. 1024 rows.
__global__ void gate_ln_k(const float* __restrict__ parts, const float* __restrict__ gate,
                          float* __restrict__ parts1, u16* __restrict__ ph) {
  int row = blockIdx.x * 4 + (threadIdx.x >> 6);
  int lane = threadIdx.x & 63;
  float g = 1.0f + gate[row];
  const float* ip = parts + (long)row * CC;
  float* op1 = parts1 + (long)row * CC;
  float v[12];
  float s = 0.f, sq = 0.f;
  for (int i = 0; i < 12; ++i) {
    float f = ip[lane + i * 64] * g;
    v[i] = f; op1[lane + i * 64] = f;
    s += f; sq += f * f;
  }
  for (int o = 32; o; o >>= 1) { s += __shfl_xor(s, o); sq += __shfl_xor(sq, o); }
  float mean = s * (1.0f / 768.0f);
  float var = sq * (1.0f / 768.0f) - mean * mean;
  float rstd = rsqrtf(var + 1e-5f);
  u16* op = ph + (long)row * CC;
  for (int i = 0; i < 12; ++i) op[lane + i * 64] = f2b((v[i] - mean) * rstd);
}

// ---------------- LN rows (C=768), wave per row, bf16 out ----------------
template <typename T>
__global__ void ln_rows_k(const T* __restrict__ in, u16* __restrict__ outp, int rows) {
  int row = blockIdx.x * 4 + (threadIdx.x >> 6);
  if (row >= rows) return;
  int lane = threadIdx.x & 63;
  const T* ip = in + (long)row * CC;
  float v[12];
  float s = 0.f, sq = 0.f;
  for (int i = 0; i < 12; ++i) {
    float f;
    if constexpr (sizeof(T) == 2) f = b2f(((const u16*)ip)[lane + i * 64]);
    else f = ((const float*)ip)[lane + i * 64];
    v[i] = f; s += f; sq += f * f;
  }
  for (int o = 32; o; o >>= 1) { s += __shfl_xor(s, o); sq += __shfl_xor(sq, o); }
  float mean = s * (1.0f / 768.0f);
  float var = sq * (1.0f / 768.0f) - mean * mean;
  float rstd = rsqrtf(var + 1e-5f);
  u16* op = outp + (long)row * CC;
  for (int i = 0; i < 12; ++i) op[lane + i * 64] = f2b((v[i] - mean) * rstd);
}

// ---------------- enc softmax ----------------
__global__ void softmax_enc_k(const float* __restrict__ attn, u16* __restrict__ sm,
                              float* __restrict__ attn0) {
  int row = blockIdx.x * 4 + (threadIdx.x >> 6);
  int lane = threadIdx.x & 63;
  const float* ap = attn + (long)row * PP;
  float v[32];
  float m = -1e30f;
  for (int i = 0; i < 32; ++i) { v[i] = ap[lane + i * 64]; m = fmaxf(m, v[i]); }
  for (int o = 32; o; o >>= 1) m = fmaxf(m, __shfl_xor(m, o));
  float s = 0.f;
  for (int i = 0; i < 32; ++i) { float e = expf(v[i] - m); v[i] = e; s += e; }
  for (int o = 32; o; o >>= 1) s += __shfl_xor(s, o);
  float inv = 1.0f / s;
  u16* sp = sm + (long)row * PP;
  for (int i = 0; i < 32; ++i) sp[lane + i * 64] = f2b(v[i] * inv);
  if (lane == 0) attn0[row] = m;
}

// split-K reduce: pv_e = bf16(sum of 4 f32 partials)
__global__ void pvred_k(const float* __restrict__ part, u16* __restrict__ outp) {
  long i = (long)blockIdx.x * 256 + threadIdx.x;
  const f32x4* p = (const f32x4*)part;
  f32x4 a = p[i];
  a += p[i + 196608];
  a += p[i + 2 * 196608];
  a += p[i + 3 * 196608];
  u32 lo = (u32)f2b(a.x) | ((u32)f2b(a.y) << 16);
  u32 hi = (u32)f2b(a.z) | ((u32)f2b(a.w) << 16);
  ((u32*)outp)[i * 2] = lo;
  ((u32*)outp)[i * 2 + 1] = hi;
}

// ---------- FAST GEMM (m97): C = A[M,K](lda)*B[N,K]^T, M,N%128==0, K%32==0
// EPI: 0 bias?->bf16 | 1 bias+gelu->bf16 | 4 bias+res32->f32
template <int EPI>
__global__ __launch_bounds__(256) void gemmf_k(
    const u16* __restrict__ A, const u16* __restrict__ Bm, void* __restrict__ Cm,
    const float* __restrict__ bias, int M, int N, int K, int lda,
    const float* __restrict__ res32) {
  __shared__ __align__(16) u16 As[128 * 32];
  __shared__ __align__(16) u16 Bs[128 * 32];
  const int nbx = N >> 7;
  const int nwg = gridDim.x;
  int tile = blockIdx.x;
  if ((nwg & 7) == 0) {
    tile = (tile & 7) * (nwg >> 3) + (tile >> 3);
  }
  const int bm0 = (tile / nbx) << 7;
  const int bn0 = (tile % nbx) << 7;
  const int tid = threadIdx.x;
  const int lane = tid & 63;
  const int wave = tid >> 6;
  const int laneq = lane & 15, lanek = lane >> 4;
  const int wm = (wave >> 1) << 6, wn = (wave & 1) << 6;
  const int srow = wave * 32 + (lane >> 2);
  const int scol = (lane & 3) << 3;
  const u16* Ag0 = A + (long)(bm0 + srow) * lda + scol;
  const u16* Ag1 = A + (long)(bm0 + srow + 16) * lda + scol;
  const u16* Bg0 = Bm + (long)(bn0 + srow) * K + scol;
  const u16* Bg1 = Bm + (long)(bn0 + srow + 16) * K + scol;
  u16* lA0 = As + wave * 1024;
  u16* lA1 = As + wave * 1024 + 512;
  u16* lB0 = Bs + wave * 1024;
  u16* lB1 = Bs + wave * 1024 + 512;
  f32x4 acc[4][4] = {};
  for (int k0 = 0; k0 < K; k0 += 32) {
    gl_lds16(Ag0 + k0, lA0);
    gl_lds16(Ag1 + k0, lA1);
    gl_lds16(Bg0 + k0, lB0);
    gl_lds16(Bg1 + k0, lB1);
    __syncthreads();
    bf16x8 af[4], bfr[4];
#pragma unroll
    for (int i = 0; i < 4; ++i)
      af[i] = *(const bf16x8*)(As + (wm + i * 16 + laneq) * 32 + (lanek << 3));
#pragma unroll
    for (int i = 0; i < 4; ++i)
      bfr[i] = *(const bf16x8*)(Bs + (wn + i * 16 + laneq) * 32 + (lanek << 3));
#pragma unroll
    for (int mi = 0; mi < 4; ++mi)
#pragma unroll
      for (int ni = 0; ni < 4; ++ni)
        acc[mi][ni] =
            __builtin_amdgcn_mfma_f32_16x16x32_bf16(af[mi], bfr[ni], acc[mi][ni], 0, 0, 0);
    __syncthreads();
  }
#pragma unroll
  for (int mi = 0; mi < 4; ++mi) {
#pragma unroll
    for (int r = 0; r < 4; ++r) {
      const int row = bm0 + wm + mi * 16 + (lanek << 2) + r;
#pragma unroll
      for (int ni = 0; ni < 4; ++ni) {
        const int col = bn0 + wn + ni * 16 + laneq;
        float v = acc[mi][ni][r] + (bias ? bias[col] : 0.f);
        long off = (long)row * N + col;
        if constexpr (EPI == 0) {
          ((u16*)Cm)[off] = f2b(v);
        } else if constexpr (EPI == 1) {
          ((u16*)Cm)[off] = f2b(gelu_f(v));
        } else {
          ((float*)Cm)[off] = v + res32[off];
        }
      }
    }
  }
}

// batched 4x 768^3 weight-product GEMM: C[z] = A[z]@B[z]^T (bf16 out, no bias)
struct G4 { const u16* A[4]; const u16* B[4]; u16* C[4]; };
__global__ __launch_bounds__(256) void gemmf4_k(G4 a) {
  __shared__ __align__(16) u16 As[128 * 32];
  __shared__ __align__(16) u16 Bs[128 * 32];
  const int z = blockIdx.x / 36;
  const int r = blockIdx.x % 36;
  const u16* A = a.A[z];
  const u16* Bm = a.B[z];
  u16* Cm = a.C[z];
  const int bm0 = (r / 6) << 7;
  const int bn0 = (r % 6) << 7;
  const int tid = threadIdx.x;
  const int lane = tid & 63;
  const int wave = tid >> 6;
  const int laneq = lane & 15, lanek = lane >> 4;
  const int wm = (wave >> 1) << 6, wn = (wave & 1) << 6;
  const int srow = wave * 32 + (lane >> 2);
  const int scol = (lane & 3) << 3;
  const u16* Ag0 = A + (long)(bm0 + srow) * CC + scol;
  const u16* Ag1 = A + (long)(bm0 + srow + 16) * CC + scol;
  const u16* Bg0 = Bm + (long)(bn0 + srow) * CC + scol;
  const u16* Bg1 = Bm + (long)(bn0 + srow + 16) * CC + scol;
  u16* lA0 = As + wave * 1024;
  u16* lA1 = As + wave * 1024 + 512;
  u16* lB0 = Bs + wave * 1024;
  u16* lB1 = Bs + wave * 1024 + 512;
  f32x4 acc[4][4] = {};
  for (int k0 = 0; k0 < CC; k0 += 32) {
    gl_lds16(Ag0 + k0, lA0);
    gl_lds16(Ag1 + k0, lA1);
    gl_lds16(Bg0 + k0, lB0);
    gl_lds16(Bg1 + k0, lB1);
    __syncthreads();
    bf16x8 af[4], bfr[4];
#pragma unroll
    for (int i = 0; i < 4; ++i)
      af[i] = *(const bf16x8*)(As + (wm + i * 16 + laneq) * 32 + (lanek << 3));
#pragma unroll
    for (int i = 0; i < 4; ++i)
      bfr[i] = *(const bf16x8*)(Bs + (wn + i * 16 + laneq) * 32 + (lanek << 3));
#pragma unroll
    for (int mi = 0; mi < 4; ++mi)
#pragma unroll
      for (int ni = 0; ni < 4; ++ni)
        acc[mi][ni] =
            __builtin_amdgcn_mfma_f32_16x16x32_bf16(af[mi], bfr[ni], acc[mi][ni], 0, 0, 0);
    __syncthreads();
  }
#pragma unroll
  for (int mi = 0; mi < 4; ++mi)
#pragma unroll
    for (int r2 = 0; r2 < 4; ++r2) {
      const int row = bm0 + wm + mi * 16 + (lanek << 2) + r2;
#pragma unroll
      for (int ni = 0; ni < 4; ++ni) {
        const int col = bn0 + wn + ni * 16 + laneq;
        Cm[(long)row * CC + col] = f2b(acc[mi][ni][r2]);
      }
    }
}

// ---------- 256x256 8-phase GEMM: C = A[M,K]*B[N,K]^T (FFN-down) ---------
#define G256_BAR() __builtin_amdgcn_s_barrier()
#define G256_WLGKM0()                                    \
  do {                                                   \
    asm volatile("s_waitcnt lgkmcnt(0)" ::: "memory");   \
    __builtin_amdgcn_sched_barrier(0);                   \
  } while (0)
#define G256_RD_A(HALF)                                                        \
  _Pragma("unroll") for (int m2 = 0; m2 < 4; ++m2) {                           \
    af[m2 * 2 + 0] = *(const bf16x8*)(Ab + ar + (HALF)*4096 + m2 * 1024 + g0); \
    af[m2 * 2 + 1] = *(const bf16x8*)(Ab + ar + (HALF)*4096 + m2 * 1024 + g1); \
  }
#define G256_RD_B(HALF, BFR)                                                   \
  _Pragma("unroll") for (int n2 = 0; n2 < 2; ++n2) {                           \
    BFR[n2 * 2 + 0] = *(const bf16x8*)(Bb + br + (HALF)*2048 + n2 * 1024 + g0);\
    BFR[n2 * 2 + 1] = *(const bf16x8*)(Bb + br + (HALF)*2048 + n2 * 1024 + g1);\
  }
#define G256_MFMA_Q(H, NH, BFR)                                                \
  __builtin_amdgcn_s_setprio(1);                                               \
  _Pragma("unroll") for (int m2 = 0; m2 < 4; ++m2)                             \
  _Pragma("unroll") for (int n2 = 0; n2 < 2; ++n2)                             \
  _Pragma("unroll") for (int s = 0; s < 2; ++s)                                \
      acc[(H)*4 + m2][(NH)*2 + n2] = __builtin_amdgcn_mfma_f32_16x16x32_bf16(  \
          af[m2 * 2 + s], BFR[n2 * 2 + s], acc[(H)*4 + m2][(NH)*2 + n2], 0, 0, 0); \
  __builtin_amdgcn_s_setprio(0);

template <int EPI>
__global__ __launch_bounds__(512, 2) void gemm256_k(
    const u16* __restrict__ A, const u16* __restrict__ Bm, void* __restrict__ Cm,
    const float* __restrict__ bias, int M, int N, int K,
    const u16* __restrict__ rxh, const float* __restrict__ rmean,
    const float* __restrict__ rrstd, long rro, int nbm) {
  __shared__ __align__(16) u16 As[2 * 16384];
  __shared__ __align__(16) u16 Bs[2 * 16384];
  const int nbx = N >> 8;
  const int nwg = gridDim.x;
  int tile = blockIdx.x;
  if ((nwg & 7) == 0) {
    tile = (tile & 7) * (nwg >> 3) + (tile >> 3);
  }
  int bm0, bn0;
  if (nbm) {
    bm0 = (tile % nbm) << 8;
    bn0 = (tile / nbm) << 8;
  } else {
    bm0 = (tile / nbx) << 8;
    bn0 = (tile % nbx) << 8;
  }
  const int tid = threadIdx.x;
  const int lane = tid & 63;
  const int wave = tid >> 6;
  const int laneq = lane & 15, lanek = lane >> 4;
  const int wrow = (wave >> 2) << 7;
  const int wcol = (wave & 3) << 6;
  const int srow8 = lane >> 3;
  const int sg = (lane & 7) ^ srow8;
  const u16* gA = A + (long)(bm0 + wave * 8 + srow8) * K + sg * 8;
  const u16* gB = Bm + (long)(bn0 + wave * 8 + srow8) * K + sg * 8;
  const long lineK = (long)64 * K;
  const int ldsLine = wave * 512;
  const int gx = laneq & 7;
  const int g0 = ((lanek) ^ gx) << 3;
  const int g1 = ((lanek + 4) ^ gx) << 3;
  const int ar = (wrow + laneq) * 64;
  const int br = (wcol + laneq) * 64;
  f32x4 acc[8][4] = {};
  bf16x8 af[8], bfr0[4], bfr1[4];
  const int NT = K >> 6;

  {
    u16* dA = (u16*)As;
    u16* dB = (u16*)Bs;
    gl_lds16(gA, dA + ldsLine);
    gl_lds16(gA + lineK, dA + ldsLine + 4096);
    gl_lds16(gA + 2 * lineK, dA + ldsLine + 8192);
    gl_lds16(gA + 3 * lineK, dA + ldsLine + 12288);
    gl_lds16(gB, dB + ldsLine);
    gl_lds16(gB + lineK, dB + ldsLine + 4096);
    gl_lds16(gB + 2 * lineK, dB + ldsLine + 8192);
    gl_lds16(gB + 3 * lineK, dB + ldsLine + 12288);
  }
  for (int T = 0; T < NT; ++T) {
    const u16* Ab = As + (T & 1) * 16384;
    const u16* Bb = Bs + (T & 1) * 16384;
    u16* An = (u16*)As + ((T & 1) ^ 1) * 16384;
    u16* Bn = (u16*)Bs + ((T & 1) ^ 1) * 16384;
    const long ko = (long)(T + 1) * 64;
    const bool more = (T + 1 < NT);
    if (more) {
      gl_lds16(gA + ko, An + ldsLine);
      gl_lds16(gA + ko + lineK, An + ldsLine + 4096);
      gl_lds16(gB + ko, Bn + ldsLine);
      gl_lds16(gB + ko + lineK, Bn + ldsLine + 4096);
      asm volatile("s_waitcnt vmcnt(4)" ::: "memory");
    } else {
      asm volatile("s_waitcnt vmcnt(0)" ::: "memory");
    }
    G256_BAR();
    G256_RD_A(0);
    G256_RD_B(0, bfr0);
    G256_WLGKM0();
    G256_MFMA_Q(0, 0, bfr0);
    G256_BAR();
    if (more) {
      gl_lds16(gA + ko + 2 * lineK, An + ldsLine + 8192);
      gl_lds16(gA + ko + 3 * lineK, An + ldsLine + 12288);
      gl_lds16(gB + ko + 2 * lineK, Bn + ldsLine + 8192);
      gl_lds16(gB + ko + 3 * lineK, Bn + ldsLine + 12288);
    }
    G256_RD_B(1, bfr1);
    G256_BAR();
    G256_WLGKM0();
    G256_MFMA_Q(0, 1, bfr1);
    G256_BAR();
    G256_RD_A(1);
    G256_BAR();
    G256_WLGKM0();
    G256_MFMA_Q(1, 1, bfr1);
    G256_BAR();
    G256_MFMA_Q(1, 0, bfr0);
  }

#pragma unroll
  for (int mi = 0; mi < 8; ++mi) {
#pragma unroll
    for (int r = 0; r < 4; ++r) {
      const int row = bm0 + wrow + mi * 16 + (lanek << 2) + r;
      float mn = 0.f, istd = 0.f;
      if constexpr (EPI == 3) {
        long gr = rro + row;
        mn = rmean[gr];
        istd = 1.0f / rrstd[gr];
      }
#pragma unroll
      for (int ni = 0; ni < 4; ++ni) {
        const int col = bn0 + wcol + ni * 16 + laneq;
        float v = acc[mi][ni][r] + bias[col];
        long off = (long)row * N + col;
        if constexpr (EPI == 0) {
          ((u16*)Cm)[off] = f2b(v);
        } else if constexpr (EPI == 1) {
          ((u16*)Cm)[off] = f2b(gelu_f(v));
        } else {
          v += b2f(rxh[(rro + row) * 768 + col]) * istd + mn;
          ((u16*)Cm)[off] = f2b(v);
        }
      }
    }
  }
}

// ---------------- GEMM (general/batched path, attention ops) ----------------
// BNT=true : B is [N,K] rows stride ldB. BNT=false: B is [K,N], k-stride ldB.
// EPI: 2 relu(acc+radd[bz*M+row])*scale->f32 | 4 raw f32 split-K
//      5 bias + transposed residual store (fuses final transpose)
//      6 relu(acc+radd[bz*N+col])*scale + full-row softmax -> bf16 (TN == N)
template <int EPI, bool BNT, int TM, int TN>
__global__ __launch_bounds__(256) void gemm_k(
    const u16* __restrict__ A, const u16* __restrict__ Bm, void* __restrict__ Cm,
    const float* __restrict__ bias, int M, int N, int kLen, int lda, int ldB,
    long sA, long sB, long sC, float scale, const float* __restrict__ res32,
    const float* __restrict__ radd) {
  __shared__ __align__(16) u16 As[TM][40];
  __shared__ __align__(16) u16 Bs[TN][40];
  const int bn0 = blockIdx.x * TN;
  const int bm0 = (EPI == 4) ? 0 : blockIdx.y * TM;
  const int kOff = (EPI == 4) ? blockIdx.y * kLen : 0;
  const int bz = blockIdx.z;
  const u16* Ab = A + (long)bz * sA;
  const u16* Bb = Bm + (long)bz * sB;
  const long coff = (EPI == 4) ? ((long)blockIdx.y * gridDim.z + bz) * sC
                               : (long)bz * sC;
  const int tid = threadIdx.x;
  const int lane = tid & 63;
  const int wave = tid >> 6;
  const int wm = (TM == 64) ? 0 : ((TN == 64) ? wave * 32 : ((wave >> 1) << 6));
  const int wn = (TN == 64) ? 0 : ((TM == 64) ? wave * 32 : ((wave & 1) << 6));
  constexpr int MI = (TN == 64) ? 2 : 4;
  constexpr int NI = (TM == 64) ? 2 : 4;
  const int laneq = lane & 15, lanek = lane >> 4;
  f32x4 acc[MI][NI] = {};
  for (int k0 = 0; k0 < kLen; k0 += 32) {
    __syncthreads();
#pragma unroll
    for (int j = 0; j < TM / 64; ++j) {
      int v = tid + j * 256;
      int m = v >> 2, kcl = (v & 3) << 3;
      u32x4 val = {0, 0, 0, 0};
      if (bm0 + m < M)
        val = *(const u32x4*)(Ab + (long)(bm0 + m) * lda + kOff + k0 + kcl);
      *(u32x4*)(&As[m][kcl]) = val;
    }
    if constexpr (BNT) {
#pragma unroll
      for (int j = 0; j < TN / 64; ++j) {
        int v = tid + j * 256;
        int n = v >> 2, kcl = (v & 3) << 3;
        u32x4 val = {0, 0, 0, 0};
        if (bn0 + n < N)
          val = *(const u32x4*)(Bb + (long)(bn0 + n) * ldB + kOff + k0 + kcl);
        *(u32x4*)(&Bs[n][kcl]) = val;
      }
    } else {
      constexpr int CCH = TN / 8;
#pragma unroll
      for (int j = 0; j < TN / 64; ++j) {
        int v = tid + j * 256;
        int kk = v / CCH, nc = (v % CCH) << 3;
        u32x4 val = {0, 0, 0, 0};
        if (bn0 + nc < N)
          val = *(const u32x4*)(Bb + (long)(kOff + k0 + kk) * ldB + bn0 + nc);
        union { u32x4 v4; u16 u[8]; } uu;
        uu.v4 = val;
#pragma unroll
        for (int e = 0; e < 8; ++e) Bs[nc + e][kk] = uu.u[e];
      }
    }
    __syncthreads();
    bf16x8 af[MI], bfr[NI];
#pragma unroll
    for (int i = 0; i < MI; ++i)
      af[i] = *(const bf16x8*)(&As[wm + i * 16 + laneq][lanek << 3]);
#pragma unroll
    for (int i = 0; i < NI; ++i)
      bfr[i] = *(const bf16x8*)(&Bs[wn + i * 16 + laneq][lanek << 3]);
#pragma unroll
    for (int mi = 0; mi < MI; ++mi)
#pragma unroll
      for (int ni = 0; ni < NI; ++ni)
        acc[mi][ni] =
            __builtin_amdgcn_mfma_f32_16x16x32_bf16(af[mi], bfr[ni], acc[mi][ni], 0, 0, 0);
  }
  if constexpr (EPI == 5) {
    __syncthreads();
    float* smem = (float*)(wave < 2 ? (void*)As : (void*)Bs) + (wave & 1) * 1024;
    const int pbase = bm0 + wm + (lane & 3) * 16;
    const long obase = (long)bz * CC * PP;
#pragma unroll
    for (int ni = 0; ni < 4; ++ni) {
#pragma unroll
      for (int mi = 0; mi < 4; ++mi)
#pragma unroll
        for (int r = 0; r < 4; ++r) {
          const int col = bn0 + wn + ni * 16 + laneq;
          smem[(mi * 16 + (lanek << 2) + r) * 16 + laneq] = acc[mi][ni][r] + bias[col];
        }
      const int c = bn0 + wn + ni * 16 + (lane >> 2);
      const float* xs = res32 + obase + (long)c * PP + pbase;
      float* os = (float*)Cm + obase + (long)c * PP + pbase;
      const float* sr = smem + (lane & 3) * 256 + (lane >> 2);
#pragma unroll
      for (int q4 = 0; q4 < 4; ++q4) {
        f32x4 xv = *(const f32x4*)(xs + q4 * 4);
        f32x4 ov;
        ov.x = sr[(q4 * 4 + 0) * 16] + xv.x;
        ov.y = sr[(q4 * 4 + 1) * 16] + xv.y;
        ov.z = sr[(q4 * 4 + 2) * 16] + xv.z;
        ov.w = sr[(q4 * 4 + 3) * 16] + xv.w;
        *(f32x4*)(os + q4 * 4) = ov;
      }
    }
  } else if constexpr (EPI == 6) {
#pragma unroll
    for (int mi = 0; mi < MI; ++mi) {
#pragma unroll
      for (int r = 0; r < 4; ++r) {
        float e[NI];
        float mx = -1e30f;
#pragma unroll
        for (int ni = 0; ni < NI; ++ni) {
          const int col = bn0 + wn + ni * 16 + laneq;
          float v = acc[mi][ni][r] + (radd ? radd[(long)bz * N + col] : 0.f);
          v = fmaxf(v, 0.0f) * scale;
          e[ni] = v;
          mx = fmaxf(mx, v);
        }
        mx = fmaxf(mx, __shfl_xor(mx, 1));
        mx = fmaxf(mx, __shfl_xor(mx, 2));
        mx = fmaxf(mx, __shfl_xor(mx, 4));
        mx = fmaxf(mx, __shfl_xor(mx, 8));
        float s = 0.f;
#pragma unroll
        for (int ni = 0; ni < NI; ++ni) { e[ni] = __expf(e[ni] - mx); s += e[ni]; }
        s += __shfl_xor(s, 1);
        s += __shfl_xor(s, 2);
        s += __shfl_xor(s, 4);
        s += __shfl_xor(s, 8);
        float inv = 1.0f / s;
        const int row = bm0 + wm + mi * 16 + (lanek << 2) + r;
#pragma unroll
        for (int ni = 0; ni < NI; ++ni) {
          const int col = bn0 + wn + ni * 16 + laneq;
          ((u16*)Cm)[coff + (long)row * N + col] = f2b(e[ni] * inv);
        }
      }
    }
  } else {
#pragma unroll
    for (int mi = 0; mi < MI; ++mi) {
#pragma unroll
      for (int ni = 0; ni < NI; ++ni) {
        int col = bn0 + wn + ni * 16 + laneq;
        if (col >= N) continue;
#pragma unroll
        for (int r = 0; r < 4; ++r) {
          int row = bm0 + wm + mi * 16 + (lanek << 2) + r;
          if (row >= M) continue;
          float v = acc[mi][ni][r];
          long off = coff + (long)row * N + col;
          if constexpr (EPI == 2) {
            v += radd ? radd[(long)bz * M + row] : 0.f;
            ((float*)Cm)[off] = fmaxf(v, 0.0f) * scale;
          } else {
            ((float*)Cm)[off] = v;
          }
        }
      }
    }
  }
}

extern "C" void kernel_launch(void* const* d_in, const int* in_sizes, int n_in,
                              void* d_out, int out_size, void* d_ws, size_t ws_size,
                              hipStream_t stream) {
  (void)in_sizes; (void)n_in; (void)out_size;
  const float* x        = (const float*)d_in[0];
  const float* parts    = (const float*)d_in[1];
  const float* enc_nq_g = (const float*)d_in[2];
  const float* enc_nq_b = (const float*)d_in[3];
  const float* enc_nk_g = (const float*)d_in[4];
  const float* enc_nk_b = (const float*)d_in[5];
  const float* enc_nv_g = (const float*)d_in[6];
  const float* enc_nv_b = (const float*)d_in[7];
  const float* enc_wq   = (const float*)d_in[8];
  const float* enc_wk   = (const float*)d_in[9];
  const float* enc_wv   = (const float*)d_in[10];
  const float* enc_wp   = (const float*)d_in[11];
  const float* enc_bq   = (const float*)d_in[12];
  const float* enc_bk   = (const float*)d_in[13];
  const float* enc_bv   = (const float*)d_in[14];
  const float* enc_bp   = (const float*)d_in[15];
  const float* dec_nq_g = (const float*)d_in[16];
  const float* dec_nq_b = (const float*)d_in[17];
  const float* dec_nk_g = (const float*)d_in[18];
  const float* dec_nk_b = (const float*)d_in[19];
  const float* dec_nv_g = (const float*)d_in[20];
  const float* dec_nv_b = (const float*)d_in[21];
  const float* dec_wq   = (const float*)d_in[22];
  const float* dec_wk   = (const float*)d_in[23];
  const float* dec_wv   = (const float*)d_in[24];
  const float* dec_wp   = (const float*)d_in[25];
  const float* dec_bq   = (const float*)d_in[26];
  const float* dec_bk   = (const float*)d_in[27];
  const float* dec_bv   = (const float*)d_in[28];
  const float* dec_bp   = (const float*)d_in[29];
  const float* ffn_ng   = (const float*)d_in[30];
  const float* ffn_nb   = (const float*)d_in[31];
  const float* ffn_w1   = (const float*)d_in[32];
  const float* ffn_b1   = (const float*)d_in[33];
  const float* ffn_w2   = (const float*)d_in[34];
  const float* ffn_b2   = (const float*)d_in[35];
  const float* sr_w1    = (const float*)d_in[36];
  const float* sr_b1    = (const float*)d_in[37];
  const float* sr_w2    = (const float*)d_in[38];
  const float* sr_b2    = (const float*)d_in[39];
  float* outp = (float*)d_out;

  char* base = (char*)d_ws;
  size_t used = 0;
  auto alloc = [&](size_t bytes) -> void* {
    void* p = base + used;
    used += (bytes + 255) & ~(size_t)255;
    return p;
  };
  const long MC = (long)CC * CC;
  u16* WpeT = (u16*)alloc(MC * 2);
  u16* WpdT = (u16*)alloc(MC * 2);
  u16* W1T  = (u16*)alloc((long)CC * FF * 2);
  u16* W2T  = (u16*)alloc((long)CC * FF * 2);
  u16* WkR  = (u16*)alloc(MC * 2);   // scaled copies (row = input dim)
  u16* WqR  = (u16*)alloc(MC * 2);
  u16* WvS  = (u16*)alloc(MC * 2);
  u16* WqdR = (u16*)alloc(MC * 2);
  u16* WkdR = (u16*)alloc(MC * 2);
  u16* WvdR = (u16*)alloc(MC * 2);
  u16* m2w  = (u16*)alloc(MC * 2);   // (Wv' Wp_enc) for pv-out
  u16* Bqk  = (u16*)alloc(MC * 2);   // enc q->score combined weight
  u16* Bgv  = (u16*)alloc(MC * 2 * 2);  // dec combined weights: Bg rows | Bv rows
  float* bqe  = (float*)alloc(CC * 4);
  float* bke  = (float*)alloc(CC * 4);
  float* bve  = (float*)alloc(CC * 4);
  float* bqd  = (float*)alloc(CC * 4);
  float* bkd  = (float*)alloc(CC * 4);
  float* bvd  = (float*)alloc(CC * 4);
  float* b1f  = (float*)alloc(FF * 4);
  float* bias2   = (float*)alloc(CC * 4);
  float* bias_gv = (float*)alloc(2 * CC * 4);   // bias_g | bias_vw
  float* bq2     = (float*)alloc(CC * 4);
  float* wqb     = (float*)alloc(CC * 4);
  float* wkb     = (float*)alloc(CC * 4);
  float* cq      = (float*)alloc(256);
  float* ck      = (float*)alloc(256);
  float* meanx = (float*)alloc((long)BB * PP * 4);
  float* rstdx = (float*)alloc((long)BB * PP * 4);
  const long BPC = (long)BB * PP * CC;
  u16* bufA = (u16*)alloc(BPC * 2);          // xhat
  u16* bufB = (u16*)alloc(BPC * 2);          // feats1 -> f1hat
  const long PC = (long)BB * 64 * CC;
  float* parts1   = (float*)alloc(PC * 4);
  float* gateb    = (float*)alloc((long)BB * 64 * 4);
  u16*   p1hat    = (u16*)alloc(PC * 2);
  u16*   qtil     = (u16*)alloc(PC * 2);
  float* qdotv    = (float*)alloc((long)BB * 64 * 4);
  float* attn_e   = (float*)alloc((long)BB * 64 * PP * 4);
  u16*   sm_e     = (u16*)alloc((long)BB * 64 * PP * 2);
  u16*   pv_e     = (u16*)alloc(PC * 2);
  float* pvpart   = (float*)alloc((long)4 * PC * 4);
  float* parts_in = (float*)alloc(PC * 4);
  u16*   pin_hat  = (u16*)alloc(PC * 2);
  u16*   GVW      = (u16*)alloc(PC * 2 * 2); // interleaved [1024][1536]: G | VW
  float* kdotv    = (float*)alloc((long)BB * 64 * 4);
  u16*   sm_d     = (u16*)alloc((long)BB * PP * 64 * 2);
  int chunk_rows = 16384;
  while (chunk_rows > 4096 &&
         used + (size_t)chunk_rows * FF * 2 > ws_size)
    chunk_rows >>= 1;
  u16* ff1 = (u16*)alloc((long)chunk_rows * FF * 2);
  if (used > ws_size) return;

  const float scale = 0.03608439182435161f;  // 768^-0.5
  dim3 blk(256);
  dim3 blk2(512);

  // 1) weight prep: transposes+scaled copies (1 launch), bias fuses, dots,
  //    batched 768^3 weight products {m2w, Bqk, Bg, Bv}
  {
    Wtr10 wa;
    const float* Ws[10] = {enc_wp, dec_wp, ffn_w1, ffn_w2, enc_wk,
                           enc_wq, enc_wv, dec_wq, dec_wk, dec_wv};
    const float* gs[10] = {nullptr, nullptr, ffn_ng, nullptr, enc_nk_g,
                           enc_nq_g, enc_nv_g, dec_nq_g, dec_nk_g, dec_nv_g};
    u16* Os[10] = {WpeT, WpdT, W1T, W2T, WkR, WqR, WvS, WqdR, WkdR, WvdR};
    int Ks[10] = {CC, CC, CC, FF, CC, CC, CC, CC, CC, CC};
    int Ns[10] = {CC, CC, FF, CC, CC, CC, CC, CC, CC, CC};
    int tr[10] = {1, 1, 1, 1, 0, 0, 0, 0, 0, 0};
    int cum = 0;
    for (int i = 0; i < 10; ++i) {
      wa.W[i] = Ws[i]; wa.g[i] = gs[i]; wa.O[i] = Os[i];
      wa.Kd[i] = Ks[i]; wa.Nd[i] = Ns[i]; wa.tr[i] = tr[i];
      wa.cum[i] = cum;
      cum += (Ns[i] / 64) * (Ks[i] / 64);
    }
    wa.cum[10] = cum;
    wtr10_k<<<cum, blk, 0, stream>>>(wa);
    Bf7 ba;
    const float* bs[7] = {enc_bq, enc_bk, enc_bv, dec_bq, dec_bk, dec_bv, ffn_b1};
    const float* nbs[7] = {enc_nq_b, enc_nk_b, enc_nv_b, dec_nq_b, dec_nk_b,
                           dec_nv_b, ffn_nb};
    const float* ws[7] = {enc_wq, enc_wk, enc_wv, dec_wq, dec_wk, dec_wv, ffn_w1};
    float* os[7] = {bqe, bke, bve, bqd, bkd, bvd, b1f};
    for (int i = 0; i < 7; ++i) {
      ba.b[i] = bs[i]; ba.nb[i] = nbs[i]; ba.W[i] = ws[i]; ba.o[i] = os[i];
      ba.Kd[i] = CC; ba.Nd[i] = (i == 6) ? FF : CC;
    }
    bfuse7_k<<<120, blk, 0, stream>>>(ba);
    Bf2 b2a;
    b2a.b[0] = enc_bp;  b2a.nb[0] = bve; b2a.W[0] = enc_wp; b2a.o[0] = bias2;
    b2a.b[1] = nullptr; b2a.nb[1] = bvd; b2a.W[1] = dec_wp; b2a.o[1] = bias_gv + CC;
    bfuse2_k<<<24, blk, 0, stream>>>(b2a);
    Dw4 da;
    da.A[0] = WkR;  da.v[0] = bqe; da.o[0] = bq2;      // bq2[c]=WkR[c,:].bqe
    da.A[1] = WqR;  da.v[1] = bke; da.o[1] = wqb;      // wqb[d]=WqR[d,:].bke
    da.A[2] = WqdR; da.v[2] = bkd; da.o[2] = bias_gv;  // bias_g[c]=WqdR[c,:].bkd
    da.A[3] = WkdR; da.v[3] = bqd; da.o[3] = wkb;      // wkb[d]=WkdR[d,:].bqd
    dotw4_k<<<768, blk, 0, stream>>>(da);
    scal2_k<<<1, 128, 0, stream>>>(bqe, bke, cq, bkd, bqd, ck);
    G4 ga;
    ga.A[0] = WpeT; ga.B[0] = WvS;  ga.C[0] = m2w;
    ga.A[1] = WkR;  ga.B[1] = WqR;  ga.C[1] = Bqk;       // Bqk[c,d]=WkR[c,:].WqR[d,:]
    ga.A[2] = WqdR; ga.B[2] = WkdR; ga.C[2] = Bgv;       // Bg[c,d]=WqdR[c,:].WkdR[d,:]
    ga.A[3] = WpdT; ga.B[3] = WvdR; ga.C[3] = Bgv + MC;  // Bv[n,d]=WpdT[n,:].WvdR[d,:]
    gemmf4_k<<<144, blk, 0, stream>>>(ga);
  }

  // 2) x LN stats + xhat transpose (single fused pass)
  xprep_k<<<dim3(32, 16), blk, 0, stream>>>(x, meanx, rstdx, bufA);

  // 3) SimpleReasoning gate; gate-apply + LN fused
  parts_gate_k<<<16, blk, 0, stream>>>(parts, sr_w1, sr_b1, sr_w2, sr_b2, gateb);
  gate_ln_k<<<256, blk, 0, stream>>>(parts, gateb, parts1, p1hat);

  // 4) enc score operand: qtil = p1hat@Bqk^T + bq2; qdot = p1hat.wqb + cq
  gemmf_k<0><<<48, blk, 0, stream>>>(p1hat, Bqk, qtil, bq2, 1024, CC, CC, CC,
      nullptr);
  dotc_k<<<256, blk, 0, stream>>>(p1hat, wqb, cq, qdotv);

  // 5) enc attention: attn = relu(qtil@xhat^T + qdot)*scale; softmax(+attn_0);
  //    pv2 = sm@xhat (split-K); parts_in = pv2@(Wv'Wp) + bias2 + parts1
  gemm_k<2, true, 64, 128><<<dim3(16, 1, 16), blk, 0, stream>>>(
      qtil, bufA, attn_e, nullptr, 64, PP, CC, CC, CC,
      (long)64 * CC, (long)PP * CC, (long)64 * PP, scale, nullptr, qdotv);
  softmax_enc_k<<<256, blk, 0, stream>>>(attn_e, sm_e, outp + (long)BB * CC * PP);
  gemm_k<4, false, 64, 128><<<dim3(6, 4, 16), blk, 0, stream>>>(
      sm_e, bufA, pvpart, nullptr, 64, CC, PP / 4, PP, CC,
      (long)64 * PP, (long)PP * CC, (long)64 * CC, 0.f, nullptr, nullptr);
  pvred_k<<<768, blk, 0, stream>>>(pvpart, pv_e);
  gemmf_k<4><<<48, blk, 0, stream>>>(pv_e, m2w, parts_in, bias2, 1024, CC, CC, CC,
      parts1);

  // 6) dec combined operands from LN(parts_in): GVW = pin_hat@Bgv^T (+bias_gv);
  //    rows interleave G cols [0,768) | VW cols [768,1536); kdot via dot
  ln_rows_k<float><<<256, blk, 0, stream>>>(parts_in, pin_hat, 1024);
  gemmf_k<0><<<96, blk, 0, stream>>>(pin_hat, Bgv, GVW, bias_gv, 1024, 2 * CC, CC,
      CC, nullptr);
  dotc_k<<<256, blk, 0, stream>>>(pin_hat, wkb, ck, kdotv);

  // 7) FFN: feats1 = x + gelu(xhat@W1'+b1')@W2 + b2  -> bufB
  //    up-proj: gemmf 128^2 @ 3 blocks/CU (K=768 regime); down: gemm256 (K=3072)
  for (long r0 = 0; r0 < 32768; r0 += chunk_rows) {
    gemmf_k<1><<<(chunk_rows / 128) * 24, blk, 0, stream>>>(
        bufA + r0 * CC, W1T, ff1, b1f, chunk_rows, FF, CC, CC, nullptr);
    gemm256_k<3><<<(chunk_rows / 256) * 3, blk2, 0, stream>>>(
        ff1, W2T, bufB + r0 * CC, ffn_b2, chunk_rows, CC, FF,
        bufA, meanx, rstdx, r0, 0);
  }
  // 8) LN(feats1) in place
  ln_rows_k<u16><<<8192, blk, 0, stream>>>(bufB, bufB, 32768);

  // 9) dec attention: sm_d = softmax(relu(f1hat@G^T + kdot)*scale)
  gemm_k<6, true, 128, 64><<<dim3(1, 16, 16), blk, 0, stream>>>(
      bufB, GVW, sm_d, nullptr, PP, 64, CC, CC, 2 * CC,
      (long)PP * CC, (long)64 * 2 * CC, (long)PP * 64, scale, nullptr, kdotv);

  // 10) fused dec output: out[b,c,p] = x[b,c,p] + (sm_d @ VW[b])[p,c] + bp[c]
  //     VW rows for batch b form B in [K=64][N=768] layout (BNT=false, ld 1536)
  gemm_k<5, false, 128, 128><<<dim3(6, 16, 16), blk, 0, stream>>>(
      sm_d, GVW + CC, outp, dec_bp, PP, CC, 64, 64, 2 * CC,
      (long)PP * 64, (long)64 * 2 * CC, 0, 0.f, x, nullptr);
}

// Round 9
// 1019.038 us; speedup vs baseline: 1.0570x; 1.0570x over previous
//
#include <hip/hip_runtime.h>

typedef unsigned short u16;
typedef unsigned int u32;
typedef __bf16 bf16x8 __attribute__((ext_vector_type(8)));
typedef float f32x4 __attribute__((ext_vector_type(4)));
typedef unsigned int u32x4 __attribute__((ext_vector_type(4)));

#define BB 16
#define CC 768
#define PP 2048
#define FF 3072

__device__ __forceinline__ float b2f(u16 u) {
  unsigned int x = ((unsigned int)u) << 16;
  return __builtin_bit_cast(float, x);
}
__device__ __forceinline__ u16 f2b(float f) {
  unsigned int x = __builtin_bit_cast(unsigned int, f);
  x += 0x7fffu + ((x >> 16) & 1u);
  return (u16)(x >> 16);
}
// erf via Abramowitz-Stegun 7.1.26 (|err|<=1.5e-7; invisible after bf16 round)
__device__ __forceinline__ float erf_fast(float x) {
  float ax = fabsf(x);
  float t = 1.0f / fmaf(0.3275911f, ax, 1.0f);
  float p = t * fmaf(t, fmaf(t, fmaf(t, fmaf(t, 1.061405429f, -1.453152027f),
                                     1.421413741f), -0.284496736f), 0.254829592f);
  float r = 1.0f - p * __expf(-ax * ax);
  return copysignf(r, x);
}
__device__ __forceinline__ float gelu_f(float x) {
  return 0.5f * x * (1.0f + erf_fast(x * 0.7071067811865475f));
}

typedef __attribute__((address_space(1))) const unsigned int g_u32;
typedef __attribute__((address_space(3))) unsigned int l_u32;
__device__ __forceinline__ void gl_lds16(const u16* g, u16* l) {
  __builtin_amdgcn_global_load_lds((g_u32*)g, (l_u32*)l, 16, 0, 0);
}

// --------- fused weight prep: tr: Wt[n,k]=g[k]W[k,n] | copy: Wt[k,n]=g[k]W[k,n]
struct Wtr10 {
  const float* W[10]; const float* g[10]; u16* O[10];
  int Kd[10]; int Nd[10]; int tr[10]; int cum[11];
};
__global__ void wtr10_k(Wtr10 a) {
  __shared__ float t[64][65];
  int tbid = blockIdx.x;
  int z = 0;
  while (tbid >= a.cum[z + 1]) ++z;
  int r = tbid - a.cum[z];
  const float* W = a.W[z];
  const float* g = a.g[z];
  u16* Wt = a.O[z];
  int K = a.Kd[z], N = a.Nd[z];
  int nbx = N >> 6;
  int n0 = (r % nbx) * 64, k0 = (r / nbx) * 64;
  int tx = threadIdx.x & 63, ty = threadIdx.x >> 6;
  if (!a.tr[z]) {  // scaled copy, row-major [K][N]
    for (int i = 0; i < 16; ++i) {
      int k = k0 + ty + i * 4;
      float sc = g ? g[k] : 1.0f;
      Wt[(long)k * N + n0 + tx] = f2b(W[(long)k * N + n0 + tx] * sc);
    }
    return;
  }
  for (int i = 0; i < 16; ++i) {
    int k = k0 + ty + i * 4;
    float sc = g ? g[k] : 1.0f;
    t[ty + i * 4][tx] = W[(long)k * N + n0 + tx] * sc;
  }
  __syncthreads();
  for (int i = 0; i < 16; ++i) {
    int n = n0 + ty + i * 4;
    Wt[(long)n * K + k0 + tx] = f2b(t[tx][ty + i * 4]);
  }
}

// fused bias prep: b'[n] = b[n] + sum_k nb[k]*W[k,n]
struct Bf7 {
  const float* b[7]; const float* nb[7]; const float* W[7]; float* o[7];
  int Kd[7]; int Nd[7];
};
__global__ void bfuse7_k(Bf7 a) {
  __shared__ float red[4][64];
  int tbid = blockIdx.x;
  int z, bx;
  if (tbid < 72) { z = tbid / 12; bx = tbid % 12; }
  else { z = 6; bx = tbid - 72; }
  const float* b = a.b[z];
  const float* nb = a.nb[z];
  const float* W = a.W[z];
  float* outb = a.o[z];
  int K = a.Kd[z], N = a.Nd[z];
  int n = bx * 64 + (threadIdx.x & 63);
  int slice = threadIdx.x >> 6;
  float acc = 0.f;
#pragma unroll 4
  for (int k = slice; k < K; k += 4) acc += nb[k] * W[(long)k * N + n];
  red[slice][threadIdx.x & 63] = acc;
  __syncthreads();
  if (slice == 0)
    outb[n] = b[n] + red[0][threadIdx.x & 63] + red[1][threadIdx.x & 63] +
              red[2][threadIdx.x & 63] + red[3][threadIdx.x & 63];
}

// 2 batched bias fuses over [768][768] f32 weights + 2 scalar dots (block 24)
struct Bf2 {
  const float* b[2]; const float* nb[2]; const float* W[2]; float* o[2];
  const float* sa0; const float* sb0; float* so0;
  const float* sa1; const float* sb1; float* so1;
};
__global__ void bfuse2_k(Bf2 a) {
  if (blockIdx.x == 24) {
    if (threadIdx.x < 128) {
      int w = threadIdx.x >> 6, lane = threadIdx.x & 63;
      const float* A = w ? a.sa1 : a.sa0;
      const float* Bv = w ? a.sb1 : a.sb0;
      float s = 0.f;
      for (int i = lane; i < CC; i += 64) s += A[i] * Bv[i];
      for (int o = 32; o; o >>= 1) s += __shfl_xor(s, o);
      if (lane == 0) *(w ? a.so1 : a.so0) = s;
    }
    return;
  }
  __shared__ float red[4][64];
  int z = blockIdx.x / 12, bx = blockIdx.x % 12;
  const float* b = a.b[z];
  const float* nb = a.nb[z];
  const float* W = a.W[z];
  int n = bx * 64 + (threadIdx.x & 63);
  int slice = threadIdx.x >> 6;
  float acc = 0.f;
#pragma unroll 4
  for (int k = slice; k < CC; k += 4) acc += nb[k] * W[(long)k * CC + n];
  red[slice][threadIdx.x & 63] = acc;
  __syncthreads();
  if (slice == 0)
    a.o[z][n] = (b ? b[n] : 0.f) + red[0][threadIdx.x & 63] +
                red[1][threadIdx.x & 63] + red[2][threadIdx.x & 63] +
                red[3][threadIdx.x & 63];
}

// 4 batched weight-row dots: o[r] = bf16 A[r,:] . vec  (768 rows each)
struct Dw4 { const u16* A[4]; const float* v[4]; float* o[4]; };
__global__ void dotw4_k(Dw4 a) {
  int z = blockIdx.x / 192;
  int row = (blockIdx.x % 192) * 4 + (threadIdx.x >> 6);
  int lane = threadIdx.x & 63;
  const u16* ip = a.A[z] + (long)row * CC;
  const float* vec = a.v[z];
  float s = 0.f;
  for (int i = 0; i < 12; ++i) s += b2f(ip[lane + i * 64]) * vec[lane + i * 64];
  for (int o = 32; o; o >>= 1) s += __shfl_xor(s, o);
  if (lane == 0) a.o[z][row] = s;
}

// out[r] = bf16 A[r,:768] . vec + *cptr   (1024 rows)
__global__ void dotc_k(const u16* __restrict__ A, const float* __restrict__ vec,
                       const float* __restrict__ cptr, float* __restrict__ outp) {
  int row = blockIdx.x * 4 + (threadIdx.x >> 6);
  int lane = threadIdx.x & 63;
  const u16* ip = A + (long)row * CC;
  float s = 0.f;
  for (int i = 0; i < 12; ++i) s += b2f(ip[lane + i * 64]) * vec[lane + i * 64];
  for (int o = 32; o; o >>= 1) s += __shfl_xor(s, o);
  if (lane == 0) outp[row] = s + cptr[0];
}

// ------- fused x prep: stats over C + transposed xhat -------
__global__ void xprep_k(const float* __restrict__ x, float* __restrict__ mean,
                        float* __restrict__ rstd, u16* __restrict__ xh) {
  __shared__ float t[64][65];
  __shared__ float red[8][64];
  __shared__ float mn_s[64], rs_s[64];
  int p0 = blockIdx.x * 64, b = blockIdx.y;
  int tx = threadIdx.x & 63, ty = threadIdx.x >> 6;
  const float* xb = x + (long)b * CC * PP;
  float s = 0.f, sq = 0.f;
  for (int c = ty; c < CC; c += 4) {
    float f = xb[(long)c * PP + p0 + tx];
    s += f; sq += f * f;
  }
  red[ty][tx] = s;
  red[4 + ty][tx] = sq;
  __syncthreads();
  if (ty == 0) {
    float S = red[0][tx] + red[1][tx] + red[2][tx] + red[3][tx];
    float Q = red[4][tx] + red[5][tx] + red[6][tx] + red[7][tx];
    float m = S * (1.0f / 768.0f);
    float var = Q * (1.0f / 768.0f) - m * m;
    float rs = rsqrtf(var + 1e-5f);
    mn_s[tx] = m; rs_s[tx] = rs;
    int gi = (b << 11) + p0 + tx;
    mean[gi] = m; rstd[gi] = rs;
  }
  __syncthreads();
  u16* ob = xh + (long)b * PP * CC;
  for (int cb = 0; cb < 12; ++cb) {
    int c0 = cb * 64;
    for (int i = 0; i < 16; ++i)
      t[ty + i * 4][tx] = xb[(long)(c0 + ty + i * 4) * PP + p0 + tx];
    __syncthreads();
    for (int i = 0; i < 16; ++i) {
      int pl = ty + i * 4;
      ob[(long)(p0 + pl) * CC + c0 + tx] = f2b((t[tx][pl] - mn_s[pl]) * rs_s[pl]);
    }
    __syncthreads();
  }
}

// ---------------- SimpleReasoning gate (compute only) ----------------
__global__ void parts_gate_k(const float* __restrict__ parts,
                             const float* __restrict__ w1, const float* __restrict__ b1,
                             const float* __restrict__ w2, const float* __restrict__ b2,
                             float* __restrict__ gate_out) {
  int b = blockIdx.x, t = threadIdx.x;
  __shared__ float g[64], g1[64];
  int r = t >> 2, l4 = t & 3;
  const float* pr = parts + ((long)b * 64 + r) * CC;
  float m = -1e30f;
  for (int c = l4; c < CC; c += 4) m = fmaxf(m, pr[c]);
  m = fmaxf(m, __shfl_xor(m, 1));
  m = fmaxf(m, __shfl_xor(m, 2));
  if (l4 == 0) g[r] = m;
  __syncthreads();
  if (t < 64) {
    float a = b1[t];
    for (int k = 0; k < 64; ++k) a += g[k] * w1[k * 64 + t];
    g1[t] = gelu_f(a);
  }
  __syncthreads();
  if (t < 64) {
    float a = b2[t];
    for (int k = 0; k < 64; ++k) a += g1[k] * w2[k * 64 + t];
    gate_out[b * 64 + t] = 1.0f / (1.0f + expf(-a));
  }
}

// gate-apply + parts1 write + LN -> p1hat, one pass. 1024 rows.
__global__ void gate_ln_k(const float* __restrict__ parts, const float* __restrict__ gate,
                          float* __restrict__ parts1, u16* __restrict__ ph) {
  int row = blockIdx.x * 4 + (threadIdx.x >> 6);
  int lane = threadIdx.x & 63;
  float g = 1.0f + gate[row];
  const float* ip = parts + (long)row * CC;
  float* op1 = parts1 + (long)row * CC;
  float v[12];
  float s = 0.f, sq = 0.f;
  for (int i = 0; i < 12; ++i) {
    float f = ip[lane + i * 64] * g;
    v[i] = f; op1[lane + i * 64] = f;
    s += f; sq += f * f;
  }
  for (int o = 32; o; o >>= 1) { s += __shfl_xor(s, o); sq += __shfl_xor(sq, o); }
  float mean = s * (1.0f / 768.0f);
  float var = sq * (1.0f / 768.0f) - mean * mean;
  float rstd = rsqrtf(var + 1e-5f);
  u16* op = ph + (long)row * CC;
  for (int i = 0; i < 12; ++i) op[lane + i * 64] = f2b((v[i] - mean) * rstd);
}

// ---------------- LN rows (C=768), wave per row, bf16 out ----------------
template <typename T>
__global__ void ln_rows_k(const T* __restrict__ in, u16* __restrict__ outp, int rows) {
  int row = blockIdx.x * 4 + (threadIdx.x >> 6);
  if (row >= rows) return;
  int lane = threadIdx.x & 63;
  const T* ip = in + (long)row * CC;
  float v[12];
  float s = 0.f, sq = 0.f;
  for (int i = 0; i < 12; ++i) {
    float f;
    if constexpr (sizeof(T) == 2) f = b2f(((const u16*)ip)[lane + i * 64]);
    else f = ((const float*)ip)[lane + i * 64];
    v[i] = f; s += f; sq += f * f;
  }
  for (int o = 32; o; o >>= 1) { s += __shfl_xor(s, o); sq += __shfl_xor(sq, o); }
  float mean = s * (1.0f / 768.0f);
  float var = sq * (1.0f / 768.0f) - mean * mean;
  float rstd = rsqrtf(var + 1e-5f);
  u16* op = outp + (long)row * CC;
  for (int i = 0; i < 12; ++i) op[lane + i * 64] = f2b((v[i] - mean) * rstd);
}

// ---------------- enc softmax ----------------
__global__ void softmax_enc_k(const float* __restrict__ attn, u16* __restrict__ sm,
                              float* __restrict__ attn0) {
  int row = blockIdx.x * 4 + (threadIdx.x >> 6);
  int lane = threadIdx.x & 63;
  const float* ap = attn + (long)row * PP;
  float v[32];
  float m = -1e30f;
  for (int i = 0; i < 32; ++i) { v[i] = ap[lane + i * 64]; m = fmaxf(m, v[i]); }
  for (int o = 32; o; o >>= 1) m = fmaxf(m, __shfl_xor(m, o));
  float s = 0.f;
  for (int i = 0; i < 32; ++i) { float e = expf(v[i] - m); v[i] = e; s += e; }
  for (int o = 32; o; o >>= 1) s += __shfl_xor(s, o);
  float inv = 1.0f / s;
  u16* sp = sm + (long)row * PP;
  for (int i = 0; i < 32; ++i) sp[lane + i * 64] = f2b(v[i] * inv);
  if (lane == 0) attn0[row] = m;
}

// split-K reduce: pv_e = bf16(sum of 4 f32 partials)
__global__ void pvred_k(const float* __restrict__ part, u16* __restrict__ outp) {
  long i = (long)blockIdx.x * 256 + threadIdx.x;
  const f32x4* p = (const f32x4*)part;
  f32x4 a = p[i];
  a += p[i + 196608];
  a += p[i + 2 * 196608];
  a += p[i + 3 * 196608];
  u32 lo = (u32)f2b(a.x) | ((u32)f2b(a.y) << 16);
  u32 hi = (u32)f2b(a.z) | ((u32)f2b(a.w) << 16);
  ((u32*)outp)[i * 2] = lo;
  ((u32*)outp)[i * 2 + 1] = hi;
}

// ---------- FAST GEMM (m97): C = A[M,K](lda)*B[N,K]^T, M,N%128==0, K%32==0
// EPI: 0 bias?->bf16 | 4 bias+res32->f32
template <int EPI>
__global__ __launch_bounds__(256) void gemmf_k(
    const u16* __restrict__ A, const u16* __restrict__ Bm, void* __restrict__ Cm,
    const float* __restrict__ bias, int M, int N, int K, int lda,
    const float* __restrict__ res32) {
  __shared__ __align__(16) u16 As[128 * 32];
  __shared__ __align__(16) u16 Bs[128 * 32];
  const int nbx = N >> 7;
  const int nwg = gridDim.x;
  int tile = blockIdx.x;
  if ((nwg & 7) == 0) {
    tile = (tile & 7) * (nwg >> 3) + (tile >> 3);
  }
  const int bm0 = (tile / nbx) << 7;
  const int bn0 = (tile % nbx) << 7;
  const int tid = threadIdx.x;
  const int lane = tid & 63;
  const int wave = tid >> 6;
  const int laneq = lane & 15, lanek = lane >> 4;
  const int wm = (wave >> 1) << 6, wn = (wave & 1) << 6;
  const int srow = wave * 32 + (lane >> 2);
  const int scol = (lane & 3) << 3;
  const u16* Ag0 = A + (long)(bm0 + srow) * lda + scol;
  const u16* Ag1 = A + (long)(bm0 + srow + 16) * lda + scol;
  const u16* Bg0 = Bm + (long)(bn0 + srow) * K + scol;
  const u16* Bg1 = Bm + (long)(bn0 + srow + 16) * K + scol;
  u16* lA0 = As + wave * 1024;
  u16* lA1 = As + wave * 1024 + 512;
  u16* lB0 = Bs + wave * 1024;
  u16* lB1 = Bs + wave * 1024 + 512;
  f32x4 acc[4][4] = {};
  for (int k0 = 0; k0 < K; k0 += 32) {
    gl_lds16(Ag0 + k0, lA0);
    gl_lds16(Ag1 + k0, lA1);
    gl_lds16(Bg0 + k0, lB0);
    gl_lds16(Bg1 + k0, lB1);
    __syncthreads();
    bf16x8 af[4], bfr[4];
#pragma unroll
    for (int i = 0; i < 4; ++i)
      af[i] = *(const bf16x8*)(As + (wm + i * 16 + laneq) * 32 + (lanek << 3));
#pragma unroll
    for (int i = 0; i < 4; ++i)
      bfr[i] = *(const bf16x8*)(Bs + (wn + i * 16 + laneq) * 32 + (lanek << 3));
#pragma unroll
    for (int mi = 0; mi < 4; ++mi)
#pragma unroll
      for (int ni = 0; ni < 4; ++ni)
        acc[mi][ni] =
            __builtin_amdgcn_mfma_f32_16x16x32_bf16(af[mi], bfr[ni], acc[mi][ni], 0, 0, 0);
    __syncthreads();
  }
#pragma unroll
  for (int mi = 0; mi < 4; ++mi) {
#pragma unroll
    for (int r = 0; r < 4; ++r) {
      const int row = bm0 + wm + mi * 16 + (lanek << 2) + r;
#pragma unroll
      for (int ni = 0; ni < 4; ++ni) {
        const int col = bn0 + wn + ni * 16 + laneq;
        float v = acc[mi][ni][r] + (bias ? bias[col] : 0.f);
        long off = (long)row * N + col;
        if constexpr (EPI == 0) {
          ((u16*)Cm)[off] = f2b(v);
        } else {
          ((float*)Cm)[off] = v + res32[off];
        }
      }
    }
  }
}

// batched 4x 768^3 weight-product GEMM: C[z] = A[z]@B[z]^T (bf16 out, no bias)
struct G4 { const u16* A[4]; const u16* B[4]; u16* C[4]; };
__global__ __launch_bounds__(256) void gemmf4_k(G4 a) {
  __shared__ __align__(16) u16 As[128 * 32];
  __shared__ __align__(16) u16 Bs[128 * 32];
  const int z = blockIdx.x / 36;
  const int r = blockIdx.x % 36;
  const u16* A = a.A[z];
  const u16* Bm = a.B[z];
  u16* Cm = a.C[z];
  const int bm0 = (r / 6) << 7;
  const int bn0 = (r % 6) << 7;
  const int tid = threadIdx.x;
  const int lane = tid & 63;
  const int wave = tid >> 6;
  const int laneq = lane & 15, lanek = lane >> 4;
  const int wm = (wave >> 1) << 6, wn = (wave & 1) << 6;
  const int srow = wave * 32 + (lane >> 2);
  const int scol = (lane & 3) << 3;
  const u16* Ag0 = A + (long)(bm0 + srow) * CC + scol;
  const u16* Ag1 = A + (long)(bm0 + srow + 16) * CC + scol;
  const u16* Bg0 = Bm + (long)(bn0 + srow) * CC + scol;
  const u16* Bg1 = Bm + (long)(bn0 + srow + 16) * CC + scol;
  u16* lA0 = As + wave * 1024;
  u16* lA1 = As + wave * 1024 + 512;
  u16* lB0 = Bs + wave * 1024;
  u16* lB1 = Bs + wave * 1024 + 512;
  f32x4 acc[4][4] = {};
  for (int k0 = 0; k0 < CC; k0 += 32) {
    gl_lds16(Ag0 + k0, lA0);
    gl_lds16(Ag1 + k0, lA1);
    gl_lds16(Bg0 + k0, lB0);
    gl_lds16(Bg1 + k0, lB1);
    __syncthreads();
    bf16x8 af[4], bfr[4];
#pragma unroll
    for (int i = 0; i < 4; ++i)
      af[i] = *(const bf16x8*)(As + (wm + i * 16 + laneq) * 32 + (lanek << 3));
#pragma unroll
    for (int i = 0; i < 4; ++i)
      bfr[i] = *(const bf16x8*)(Bs + (wn + i * 16 + laneq) * 32 + (lanek << 3));
#pragma unroll
    for (int mi = 0; mi < 4; ++mi)
#pragma unroll
      for (int ni = 0; ni < 4; ++ni)
        acc[mi][ni] =
            __builtin_amdgcn_mfma_f32_16x16x32_bf16(af[mi], bfr[ni], acc[mi][ni], 0, 0, 0);
    __syncthreads();
  }
#pragma unroll
  for (int mi = 0; mi < 4; ++mi)
#pragma unroll
    for (int r2 = 0; r2 < 4; ++r2) {
      const int row = bm0 + wm + mi * 16 + (lanek << 2) + r2;
#pragma unroll
      for (int ni = 0; ni < 4; ++ni) {
        const int col = bn0 + wn + ni * 16 + laneq;
        Cm[(long)row * CC + col] = f2b(acc[mi][ni][r2]);
      }
    }
}

// ---------- 256x256 8-phase GEMM: C = A[M,K]*B[N,K]^T (FFN) ---------
#define G256_BAR() __builtin_amdgcn_s_barrier()
#define G256_WLGKM0()                                    \
  do {                                                   \
    asm volatile("s_waitcnt lgkmcnt(0)" ::: "memory");   \
    __builtin_amdgcn_sched_barrier(0);                   \
  } while (0)
#define G256_RD_A(HALF)                                                        \
  _Pragma("unroll") for (int m2 = 0; m2 < 4; ++m2) {                           \
    af[m2 * 2 + 0] = *(const bf16x8*)(Ab + ar + (HALF)*4096 + m2 * 1024 + g0); \
    af[m2 * 2 + 1] = *(const bf16x8*)(Ab + ar + (HALF)*4096 + m2 * 1024 + g1); \
  }
#define G256_RD_B(HALF, BFR)                                                   \
  _Pragma("unroll") for (int n2 = 0; n2 < 2; ++n2) {                           \
    BFR[n2 * 2 + 0] = *(const bf16x8*)(Bb + br + (HALF)*2048 + n2 * 1024 + g0);\
    BFR[n2 * 2 + 1] = *(const bf16x8*)(Bb + br + (HALF)*2048 + n2 * 1024 + g1);\
  }
#define G256_MFMA_Q(H, NH, BFR)                                                \
  __builtin_amdgcn_s_setprio(1);                                               \
  _Pragma("unroll") for (int m2 = 0; m2 < 4; ++m2)                             \
  _Pragma("unroll") for (int n2 = 0; n2 < 2; ++n2)                             \
  _Pragma("unroll") for (int s = 0; s < 2; ++s)                                \
      acc[(H)*4 + m2][(NH)*2 + n2] = __builtin_amdgcn_mfma_f32_16x16x32_bf16(  \
          af[m2 * 2 + s], BFR[n2 * 2 + s], acc[(H)*4 + m2][(NH)*2 + n2], 0, 0, 0); \
  __builtin_amdgcn_s_setprio(0);

template <int EPI>
__global__ __launch_bounds__(512, 2) void gemm256_k(
    const u16* __restrict__ A, const u16* __restrict__ Bm, void* __restrict__ Cm,
    const float* __restrict__ bias, int M, int N, int K,
    const u16* __restrict__ rxh, const float* __restrict__ rmean,
    const float* __restrict__ rrstd, long rro) {
  __shared__ __align__(16) u16 As[2 * 16384];
  __shared__ __align__(16) u16 Bs[2 * 16384];
  const int nbx = N >> 8;
  const int nwg = gridDim.x;
  int tile = blockIdx.x;
  if ((nwg & 7) == 0) {
    tile = (tile & 7) * (nwg >> 3) + (tile >> 3);
  }
  const int bm0 = (tile / nbx) << 8;
  const int bn0 = (tile % nbx) << 8;
  const int tid = threadIdx.x;
  const int lane = tid & 63;
  const int wave = tid >> 6;
  const int laneq = lane & 15, lanek = lane >> 4;
  const int wrow = (wave >> 2) << 7;
  const int wcol = (wave & 3) << 6;
  const int srow8 = lane >> 3;
  const int sg = (lane & 7) ^ srow8;
  const u16* gA = A + (long)(bm0 + wave * 8 + srow8) * K + sg * 8;
  const u16* gB = Bm + (long)(bn0 + wave * 8 + srow8) * K + sg * 8;
  const long lineK = (long)64 * K;
  const int ldsLine = wave * 512;
  const int gx = laneq & 7;
  const int g0 = ((lanek) ^ gx) << 3;
  const int g1 = ((lanek + 4) ^ gx) << 3;
  const int ar = (wrow + laneq) * 64;
  const int br = (wcol + laneq) * 64;
  f32x4 acc[8][4] = {};
  bf16x8 af[8], bfr0[4], bfr1[4];
  const int NT = K >> 6;

  {
    u16* dA = (u16*)As;
    u16* dB = (u16*)Bs;
    gl_lds16(gA, dA + ldsLine);
    gl_lds16(gA + lineK, dA + ldsLine + 4096);
    gl_lds16(gA + 2 * lineK, dA + ldsLine + 8192);
    gl_lds16(gA + 3 * lineK, dA + ldsLine + 12288);
    gl_lds16(gB, dB + ldsLine);
    gl_lds16(gB + lineK, dB + ldsLine + 4096);
    gl_lds16(gB + 2 * lineK, dB + ldsLine + 8192);
    gl_lds16(gB + 3 * lineK, dB + ldsLine + 12288);
  }
  for (int T = 0; T < NT; ++T) {
    const u16* Ab = As + (T & 1) * 16384;
    const u16* Bb = Bs + (T & 1) * 16384;
    u16* An = (u16*)As + ((T & 1) ^ 1) * 16384;
    u16* Bn = (u16*)Bs + ((T & 1) ^ 1) * 16384;
    const long ko = (long)(T + 1) * 64;
    const bool more = (T + 1 < NT);
    if (more) {
      gl_lds16(gA + ko, An + ldsLine);
      gl_lds16(gA + ko + lineK, An + ldsLine + 4096);
      gl_lds16(gB + ko, Bn + ldsLine);
      gl_lds16(gB + ko + lineK, Bn + ldsLine + 4096);
      asm volatile("s_waitcnt vmcnt(4)" ::: "memory");
    } else {
      asm volatile("s_waitcnt vmcnt(0)" ::: "memory");
    }
    G256_BAR();
    G256_RD_A(0);
    G256_RD_B(0, bfr0);
    G256_WLGKM0();
    G256_MFMA_Q(0, 0, bfr0);
    G256_BAR();
    if (more) {
      gl_lds16(gA + ko + 2 * lineK, An + ldsLine + 8192);
      gl_lds16(gA + ko + 3 * lineK, An + ldsLine + 12288);
      gl_lds16(gB + ko + 2 * lineK, Bn + ldsLine + 8192);
      gl_lds16(gB + ko + 3 * lineK, Bn + ldsLine + 12288);
    }
    G256_RD_B(1, bfr1);
    G256_BAR();
    G256_WLGKM0();
    G256_MFMA_Q(0, 1, bfr1);
    G256_BAR();
    G256_RD_A(1);
    G256_BAR();
    G256_WLGKM0();
    G256_MFMA_Q(1, 1, bfr1);
    G256_BAR();
    G256_MFMA_Q(1, 0, bfr0);
  }

#pragma unroll
  for (int mi = 0; mi < 8; ++mi) {
#pragma unroll
    for (int r = 0; r < 4; ++r) {
      const int row = bm0 + wrow + mi * 16 + (lanek << 2) + r;
      float mn = 0.f, istd = 0.f;
      if constexpr (EPI == 3) {
        long gr = rro + row;
        mn = rmean[gr];
        istd = 1.0f / rrstd[gr];
      }
#pragma unroll
      for (int ni = 0; ni < 4; ++ni) {
        const int col = bn0 + wcol + ni * 16 + laneq;
        float v = acc[mi][ni][r] + bias[col];
        long off = (long)row * N + col;
        if constexpr (EPI == 0) {
          ((u16*)Cm)[off] = f2b(v);
        } else if constexpr (EPI == 1) {
          ((u16*)Cm)[off] = f2b(gelu_f(v));
        } else {
          v += b2f(rxh[(rro + row) * 768 + col]) * istd + mn;
          ((u16*)Cm)[off] = f2b(v);
        }
      }
    }
  }
}

// ---------------- GEMM (general/batched path, enc attention) ----------------
// BNT=true : B is [N,K] rows stride ldB. BNT=false: B is [K,N], k-stride ldB.
// EPI: 2 relu(acc+radd[bz*M+row])*scale->f32 | 4 raw f32 split-K
template <int EPI, bool BNT, int TM, int TN>
__global__ __launch_bounds__(256) void gemm_k(
    const u16* __restrict__ A, const u16* __restrict__ Bm, void* __restrict__ Cm,
    const float* __restrict__ bias, int M, int N, int kLen, int lda, int ldB,
    long sA, long sB, long sC, float scale, const float* __restrict__ res32,
    const float* __restrict__ radd) {
  __shared__ __align__(16) u16 As[TM][40];
  __shared__ __align__(16) u16 Bs[TN][40];
  const int bn0 = blockIdx.x * TN;
  const int bm0 = (EPI == 4) ? 0 : blockIdx.y * TM;
  const int kOff = (EPI == 4) ? blockIdx.y * kLen : 0;
  const int bz = blockIdx.z;
  const u16* Ab = A + (long)bz * sA;
  const u16* Bb = Bm + (long)bz * sB;
  const long coff = (EPI == 4) ? ((long)blockIdx.y * gridDim.z + bz) * sC
                               : (long)bz * sC;
  const int tid = threadIdx.x;
  const int lane = tid & 63;
  const int wave = tid >> 6;
  const int wm = (TM == 64) ? 0 : ((TN == 64) ? wave * 32 : ((wave >> 1) << 6));
  const int wn = (TN == 64) ? 0 : ((TM == 64) ? wave * 32 : ((wave & 1) << 6));
  constexpr int MI = (TN == 64) ? 2 : 4;
  constexpr int NI = (TM == 64) ? 2 : 4;
  const int laneq = lane & 15, lanek = lane >> 4;
  f32x4 acc[MI][NI] = {};
  for (int k0 = 0; k0 < kLen; k0 += 32) {
    __syncthreads();
#pragma unroll
    for (int j = 0; j < TM / 64; ++j) {
      int v = tid + j * 256;
      int m = v >> 2, kcl = (v & 3) << 3;
      u32x4 val = {0, 0, 0, 0};
      if (bm0 + m < M)
        val = *(const u32x4*)(Ab + (long)(bm0 + m) * lda + kOff + k0 + kcl);
      *(u32x4*)(&As[m][kcl]) = val;
    }
    if constexpr (BNT) {
#pragma unroll
      for (int j = 0; j < TN / 64; ++j) {
        int v = tid + j * 256;
        int n = v >> 2, kcl = (v & 3) << 3;
        u32x4 val = {0, 0, 0, 0};
        if (bn0 + n < N)
          val = *(const u32x4*)(Bb + (long)(bn0 + n) * ldB + kOff + k0 + kcl);
        *(u32x4*)(&Bs[n][kcl]) = val;
      }
    } else {
      constexpr int CCH = TN / 8;
#pragma unroll
      for (int j = 0; j < TN / 64; ++j) {
        int v = tid + j * 256;
        int kk = v / CCH, nc = (v % CCH) << 3;
        u32x4 val = {0, 0, 0, 0};
        if (bn0 + nc < N)
          val = *(const u32x4*)(Bb + (long)(kOff + k0 + kk) * ldB + bn0 + nc);
        union { u32x4 v4; u16 u[8]; } uu;
        uu.v4 = val;
#pragma unroll
        for (int e = 0; e < 8; ++e) Bs[nc + e][kk] = uu.u[e];
      }
    }
    __syncthreads();
    bf16x8 af[MI], bfr[NI];
#pragma unroll
    for (int i = 0; i < MI; ++i)
      af[i] = *(const bf16x8*)(&As[wm + i * 16 + laneq][lanek << 3]);
#pragma unroll
    for (int i = 0; i < NI; ++i)
      bfr[i] = *(const bf16x8*)(&Bs[wn + i * 16 + laneq][lanek << 3]);
#pragma unroll
    for (int mi = 0; mi < MI; ++mi)
#pragma unroll
      for (int ni = 0; ni < NI; ++ni)
        acc[mi][ni] =
            __builtin_amdgcn_mfma_f32_16x16x32_bf16(af[mi], bfr[ni], acc[mi][ni], 0, 0, 0);
  }
#pragma unroll
  for (int mi = 0; mi < MI; ++mi) {
#pragma unroll
    for (int ni = 0; ni < NI; ++ni) {
      int col = bn0 + wn + ni * 16 + laneq;
      if (col >= N) continue;
#pragma unroll
      for (int r = 0; r < 4; ++r) {
        int row = bm0 + wm + mi * 16 + (lanek << 2) + r;
        if (row >= M) continue;
        float v = acc[mi][ni][r];
        long off = coff + (long)row * N + col;
        if constexpr (EPI == 2) {
          v += radd ? radd[(long)bz * M + row] : 0.f;
          ((float*)Cm)[off] = fmaxf(v, 0.0f) * scale;
        } else {
          ((float*)Cm)[off] = v;
        }
      }
    }
  }
}

// ---------- fully fused dec attention: QK^T + softmax + PV + residual -------
// Per block: 128 q-rows (p), batch bz. fh=[B*P][768], GVW=[1024][1536]
// (G cols [0,768), VW cols [768,1536)). out[b,c,p] = x + P@VW + bias.
__global__ __launch_bounds__(256) void decattn_k(
    const u16* __restrict__ fh, const u16* __restrict__ GVW,
    const float* __restrict__ kdotv, const float* __restrict__ x,
    const float* __restrict__ bias, float* __restrict__ outp, float scale) {
  __shared__ __align__(16) u16 As[128][40];
  __shared__ __align__(16) u16 Bs[64][40];
  __shared__ __align__(16) u16 Vs[768][68];   // VW transposed: Vs[c][j]
  __shared__ __align__(16) u16 Ps[128][72];   // P bf16
  __shared__ float Ts[4][1024];               // per-wave transpose scratch
  const int bm0 = blockIdx.x * 128;
  const int bz = blockIdx.y;
  const int tid = threadIdx.x, lane = tid & 63, wave = tid >> 6;
  const int laneq = lane & 15, lanek = lane >> 4;
  // load VW[bz] transposed into Vs
  {
    const u16* vw = GVW + ((long)bz * 64) * 1536 + 768;
    for (int it = 0; it < 24; ++it) {
      int l8 = tid + it * 256;        // 0..6143
      int j = l8 / 96;                // 0..63
      int c8 = (l8 % 96) * 8;
      union { bf16x8 v; u16 u[8]; } uu;
      uu.v = *(const bf16x8*)(vw + (long)j * 1536 + c8);
#pragma unroll
      for (int e = 0; e < 8; ++e) Vs[c8 + e][j] = uu.u[e];
    }
  }
  // ---- QK^T (TM=128, TN=64): wave owns 32 rows (wm), full 64 cols
  const u16* Ab = fh + (long)bz * PP * CC;
  const u16* Bb = GVW + (long)bz * 64 * 1536;
  const int wm = wave * 32;
  f32x4 acc[2][4] = {};
  for (int k0 = 0; k0 < CC; k0 += 32) {
    __syncthreads();
#pragma unroll
    for (int j = 0; j < 2; ++j) {
      int v = tid + j * 256;
      int m = v >> 2, kcl = (v & 3) << 3;
      *(u32x4*)(&As[m][kcl]) =
          *(const u32x4*)(Ab + (long)(bm0 + m) * CC + k0 + kcl);
    }
    {
      int n = tid >> 2, kcl = (tid & 3) << 3;
      *(u32x4*)(&Bs[n][kcl]) = *(const u32x4*)(Bb + (long)n * 1536 + k0 + kcl);
    }
    __syncthreads();
    bf16x8 af[2], bfr[4];
#pragma unroll
    for (int i = 0; i < 2; ++i)
      af[i] = *(const bf16x8*)(&As[wm + i * 16 + laneq][lanek << 3]);
#pragma unroll
    for (int i = 0; i < 4; ++i)
      bfr[i] = *(const bf16x8*)(&Bs[i * 16 + laneq][lanek << 3]);
#pragma unroll
    for (int mi = 0; mi < 2; ++mi)
#pragma unroll
      for (int ni = 0; ni < 4; ++ni)
        acc[mi][ni] =
            __builtin_amdgcn_mfma_f32_16x16x32_bf16(af[mi], bfr[ni], acc[mi][ni], 0, 0, 0);
  }
  // ---- relu + row-softmax -> Ps (row lives in a 16-lane group x 4 cols)
#pragma unroll
  for (int mi = 0; mi < 2; ++mi) {
#pragma unroll
    for (int r = 0; r < 4; ++r) {
      float e[4];
      float mx = -1e30f;
#pragma unroll
      for (int ni = 0; ni < 4; ++ni) {
        const int col = ni * 16 + laneq;
        float v = acc[mi][ni][r] + kdotv[(long)bz * 64 + col];
        v = fmaxf(v, 0.0f) * scale;
        e[ni] = v;
        mx = fmaxf(mx, v);
      }
      mx = fmaxf(mx, __shfl_xor(mx, 1));
      mx = fmaxf(mx, __shfl_xor(mx, 2));
      mx = fmaxf(mx, __shfl_xor(mx, 4));
      mx = fmaxf(mx, __shfl_xor(mx, 8));
      float s = 0.f;
#pragma unroll
      for (int ni = 0; ni < 4; ++ni) { e[ni] = __expf(e[ni] - mx); s += e[ni]; }
      s += __shfl_xor(s, 1);
      s += __shfl_xor(s, 2);
      s += __shfl_xor(s, 4);
      s += __shfl_xor(s, 8);
      float inv = 1.0f / s;
      const int prow = wm + mi * 16 + (lanek << 2) + r;
#pragma unroll
      for (int ni = 0; ni < 4; ++ni)
        Ps[prow][ni * 16 + laneq] = f2b(e[ni] * inv);
    }
  }
  __syncthreads();
  // ---- PV + transposed residual store. 6 n-iters of 128 cols;
  // 4 waves as 2x2: rows (wave&1)*64, cols (wave>>1)*64 within the 128.
  const int wr = (wave & 1) << 6;
  const int wc = (wave >> 1) << 6;
  const long obase = (long)bz * CC * PP;
  const int pbase = bm0 + wr + (lane & 3) * 16;
  for (int nc = 0; nc < 6; ++nc) {
    f32x4 a2[4][4] = {};
#pragma unroll
    for (int ks = 0; ks < 2; ++ks) {
      bf16x8 af[4], bfr[4];
#pragma unroll
      for (int i = 0; i < 4; ++i)
        af[i] = *(const bf16x8*)(&Ps[wr + i * 16 + laneq][ks * 32 + (lanek << 3)]);
#pragma unroll
      for (int i = 0; i < 4; ++i)
        bfr[i] = *(const bf16x8*)(&Vs[nc * 128 + wc + i * 16 + laneq]
                                     [ks * 32 + (lanek << 3)]);
#pragma unroll
      for (int mi = 0; mi < 4; ++mi)
#pragma unroll
        for (int ni = 0; ni < 4; ++ni)
          a2[mi][ni] =
              __builtin_amdgcn_mfma_f32_16x16x32_bf16(af[mi], bfr[ni], a2[mi][ni], 0, 0, 0);
    }
    float* smem = Ts[wave];
#pragma unroll
    for (int ni = 0; ni < 4; ++ni) {
#pragma unroll
      for (int mi = 0; mi < 4; ++mi)
#pragma unroll
        for (int r = 0; r < 4; ++r) {
          const int col = nc * 128 + wc + ni * 16 + laneq;
          smem[(mi * 16 + (lanek << 2) + r) * 16 + laneq] =
              a2[mi][ni][r] + bias[col];
        }
      const int c = nc * 128 + wc + ni * 16 + (lane >> 2);
      const float* xs = x + obase + (long)c * PP + pbase;
      float* os = outp + obase + (long)c * PP + pbase;
      const float* sr = smem + (lane & 3) * 256 + (lane >> 2);
#pragma unroll
      for (int q4 = 0; q4 < 4; ++q4) {
        f32x4 xv = *(const f32x4*)(xs + q4 * 4);
        f32x4 ov;
        ov.x = sr[(q4 * 4 + 0) * 16] + xv.x;
        ov.y = sr[(q4 * 4 + 1) * 16] + xv.y;
        ov.z = sr[(q4 * 4 + 2) * 16] + xv.z;
        ov.w = sr[(q4 * 4 + 3) * 16] + xv.w;
        *(f32x4*)(os + q4 * 4) = ov;
      }
    }
  }
}

extern "C" void kernel_launch(void* const* d_in, const int* in_sizes, int n_in,
                              void* d_out, int out_size, void* d_ws, size_t ws_size,
                              hipStream_t stream) {
  (void)in_sizes; (void)n_in; (void)out_size;
  const float* x        = (const float*)d_in[0];
  const float* parts    = (const float*)d_in[1];
  const float* enc_nq_g = (const float*)d_in[2];
  const float* enc_nq_b = (const float*)d_in[3];
  const float* enc_nk_g = (const float*)d_in[4];
  const float* enc_nk_b = (const float*)d_in[5];
  const float* enc_nv_g = (const float*)d_in[6];
  const float* enc_nv_b = (const float*)d_in[7];
  const float* enc_wq   = (const float*)d_in[8];
  const float* enc_wk   = (const float*)d_in[9];
  const float* enc_wv   = (const float*)d_in[10];
  const float* enc_wp   = (const float*)d_in[11];
  const float* enc_bq   = (const float*)d_in[12];
  const float* enc_bk   = (const float*)d_in[13];
  const float* enc_bv   = (const float*)d_in[14];
  const float* enc_bp   = (const float*)d_in[15];
  const float* dec_nq_g = (const float*)d_in[16];
  const float* dec_nq_b = (const float*)d_in[17];
  const float* dec_nk_g = (const float*)d_in[18];
  const float* dec_nk_b = (const float*)d_in[19];
  const float* dec_nv_g = (const float*)d_in[20];
  const float* dec_nv_b = (const float*)d_in[21];
  const float* dec_wq   = (const float*)d_in[22];
  const float* dec_wk   = (const float*)d_in[23];
  const float* dec_wv   = (const float*)d_in[24];
  const float* dec_wp   = (const float*)d_in[25];
  const float* dec_bq   = (const float*)d_in[26];
  const float* dec_bk   = (const float*)d_in[27];
  const float* dec_bv   = (const float*)d_in[28];
  const float* dec_bp   = (const float*)d_in[29];
  const float* ffn_ng   = (const float*)d_in[30];
  const float* ffn_nb   = (const float*)d_in[31];
  const float* ffn_w1   = (const float*)d_in[32];
  const float* ffn_b1   = (const float*)d_in[33];
  const float* ffn_w2   = (const float*)d_in[34];
  const float* ffn_b2   = (const float*)d_in[35];
  const float* sr_w1    = (const float*)d_in[36];
  const float* sr_b1    = (const float*)d_in[37];
  const float* sr_w2    = (const float*)d_in[38];
  const float* sr_b2    = (const float*)d_in[39];
  float* outp = (float*)d_out;

  char* base = (char*)d_ws;
  size_t used = 0;
  auto alloc = [&](size_t bytes) -> void* {
    void* p = base + used;
    used += (bytes + 255) & ~(size_t)255;
    return p;
  };
  const long MC = (long)CC * CC;
  u16* WpeT = (u16*)alloc(MC * 2);
  u16* WpdT = (u16*)alloc(MC * 2);
  u16* W1T  = (u16*)alloc((long)CC * FF * 2);
  u16* W2T  = (u16*)alloc((long)CC * FF * 2);
  u16* WkR  = (u16*)alloc(MC * 2);   // scaled copies (row = input dim)
  u16* WqR  = (u16*)alloc(MC * 2);
  u16* WvS  = (u16*)alloc(MC * 2);
  u16* WqdR = (u16*)alloc(MC * 2);
  u16* WkdR = (u16*)alloc(MC * 2);
  u16* WvdR = (u16*)alloc(MC * 2);
  u16* m2w  = (u16*)alloc(MC * 2);   // (Wv' Wp_enc) for pv-out
  u16* Bqk  = (u16*)alloc(MC * 2);   // enc q->score combined weight
  u16* Bgv  = (u16*)alloc(MC * 2 * 2);  // dec combined weights: Bg rows | Bv rows
  float* bqe  = (float*)alloc(CC * 4);
  float* bke  = (float*)alloc(CC * 4);
  float* bve  = (float*)alloc(CC * 4);
  float* bqd  = (float*)alloc(CC * 4);
  float* bkd  = (float*)alloc(CC * 4);
  float* bvd  = (float*)alloc(CC * 4);
  float* b1f  = (float*)alloc(FF * 4);
  float* bias2   = (float*)alloc(CC * 4);
  float* bias_gv = (float*)alloc(2 * CC * 4);   // bias_g | bias_vw
  float* bq2     = (float*)alloc(CC * 4);
  float* wqb     = (float*)alloc(CC * 4);
  float* wkb     = (float*)alloc(CC * 4);
  float* cq      = (float*)alloc(256);
  float* ck      = (float*)alloc(256);
  float* meanx = (float*)alloc((long)BB * PP * 4);
  float* rstdx = (float*)alloc((long)BB * PP * 4);
  const long BPC = (long)BB * PP * CC;
  u16* bufA = (u16*)alloc(BPC * 2);          // xhat
  u16* bufB = (u16*)alloc(BPC * 2);          // feats1 -> f1hat
  const long PC = (long)BB * 64 * CC;
  float* parts1   = (float*)alloc(PC * 4);
  float* gateb    = (float*)alloc((long)BB * 64 * 4);
  u16*   p1hat    = (u16*)alloc(PC * 2);
  u16*   qtil     = (u16*)alloc(PC * 2);
  float* qdotv    = (float*)alloc((long)BB * 64 * 4);
  float* attn_e   = (float*)alloc((long)BB * 64 * PP * 4);
  u16*   sm_e     = (u16*)alloc((long)BB * 64 * PP * 2);
  u16*   pv_e     = (u16*)alloc(PC * 2);
  float* pvpart   = (float*)alloc((long)4 * PC * 4);
  float* parts_in = (float*)alloc(PC * 4);
  u16*   pin_hat  = (u16*)alloc(PC * 2);
  u16*   GVW      = (u16*)alloc(PC * 2 * 2); // interleaved [1024][1536]: G | VW
  float* kdotv    = (float*)alloc((long)BB * 64 * 4);
  int chunk_rows = 16384;
  while (chunk_rows > 4096 &&
         used + (size_t)chunk_rows * FF * 2 > ws_size)
    chunk_rows >>= 1;
  u16* ff1 = (u16*)alloc((long)chunk_rows * FF * 2);
  if (used > ws_size) return;

  const float scale = 0.03608439182435161f;  // 768^-0.5
  dim3 blk(256);
  dim3 blk2(512);

  // 1) weight prep
  {
    Wtr10 wa;
    const float* Ws[10] = {enc_wp, dec_wp, ffn_w1, ffn_w2, enc_wk,
                           enc_wq, enc_wv, dec_wq, dec_wk, dec_wv};
    const float* gs[10] = {nullptr, nullptr, ffn_ng, nullptr, enc_nk_g,
                           enc_nq_g, enc_nv_g, dec_nq_g, dec_nk_g, dec_nv_g};
    u16* Os[10] = {WpeT, WpdT, W1T, W2T, WkR, WqR, WvS, WqdR, WkdR, WvdR};
    int Ks[10] = {CC, CC, CC, FF, CC, CC, CC, CC, CC, CC};
    int Ns[10] = {CC, CC, FF, CC, CC, CC, CC, CC, CC, CC};
    int tr[10] = {1, 1, 1, 1, 0, 0, 0, 0, 0, 0};
    int cum = 0;
    for (int i = 0; i < 10; ++i) {
      wa.W[i] = Ws[i]; wa.g[i] = gs[i]; wa.O[i] = Os[i];
      wa.Kd[i] = Ks[i]; wa.Nd[i] = Ns[i]; wa.tr[i] = tr[i];
      wa.cum[i] = cum;
      cum += (Ns[i] / 64) * (Ks[i] / 64);
    }
    wa.cum[10] = cum;
    wtr10_k<<<cum, blk, 0, stream>>>(wa);
    Bf7 ba;
    const float* bs[7] = {enc_bq, enc_bk, enc_bv, dec_bq, dec_bk, dec_bv, ffn_b1};
    const float* nbs[7] = {enc_nq_b, enc_nk_b, enc_nv_b, dec_nq_b, dec_nk_b,
                           dec_nv_b, ffn_nb};
    const float* ws[7] = {enc_wq, enc_wk, enc_wv, dec_wq, dec_wk, dec_wv, ffn_w1};
    float* os[7] = {bqe, bke, bve, bqd, bkd, bvd, b1f};
    for (int i = 0; i < 7; ++i) {
      ba.b[i] = bs[i]; ba.nb[i] = nbs[i]; ba.W[i] = ws[i]; ba.o[i] = os[i];
      ba.Kd[i] = CC; ba.Nd[i] = (i == 6) ? FF : CC;
    }
    bfuse7_k<<<120, blk, 0, stream>>>(ba);
    Bf2 b2a;
    b2a.b[0] = enc_bp;  b2a.nb[0] = bve; b2a.W[0] = enc_wp; b2a.o[0] = bias2;
    b2a.b[1] = nullptr; b2a.nb[1] = bvd; b2a.W[1] = dec_wp; b2a.o[1] = bias_gv + CC;
    b2a.sa0 = bqe; b2a.sb0 = bke; b2a.so0 = cq;
    b2a.sa1 = bkd; b2a.sb1 = bqd; b2a.so1 = ck;
    bfuse2_k<<<25, blk, 0, stream>>>(b2a);
    Dw4 da;
    da.A[0] = WkR;  da.v[0] = bqe; da.o[0] = bq2;      // bq2[c]=WkR[c,:].bqe
    da.A[1] = WqR;  da.v[1] = bke; da.o[1] = wqb;      // wqb[d]=WqR[d,:].bke
    da.A[2] = WqdR; da.v[2] = bkd; da.o[2] = bias_gv;  // bias_g[c]=WqdR[c,:].bkd
    da.A[3] = WkdR; da.v[3] = bqd; da.o[3] = wkb;      // wkb[d]=WkdR[d,:].bqd
    dotw4_k<<<768, blk, 0, stream>>>(da);
    G4 ga;
    ga.A[0] = WpeT; ga.B[0] = WvS;  ga.C[0] = m2w;
    ga.A[1] = WkR;  ga.B[1] = WqR;  ga.C[1] = Bqk;       // Bqk[c,d]=WkR[c,:].WqR[d,:]
    ga.A[2] = WqdR; ga.B[2] = WkdR; ga.C[2] = Bgv;       // Bg[c,d]=WqdR[c,:].WkdR[d,:]
    ga.A[3] = WpdT; ga.B[3] = WvdR; ga.C[3] = Bgv + MC;  // Bv[n,d]=WpdT[n,:].WvdR[d,:]
    gemmf4_k<<<144, blk, 0, stream>>>(ga);
  }

  // 2) x LN stats + xhat transpose (single fused pass)
  xprep_k<<<dim3(32, 16), blk, 0, stream>>>(x, meanx, rstdx, bufA);

  // 3) SimpleReasoning gate; gate-apply + LN fused
  parts_gate_k<<<16, blk, 0, stream>>>(parts, sr_w1, sr_b1, sr_w2, sr_b2, gateb);
  gate_ln_k<<<256, blk, 0, stream>>>(parts, gateb, parts1, p1hat);

  // 4) enc score operand: qtil = p1hat@Bqk^T + bq2; qdot = p1hat.wqb + cq
  gemmf_k<0><<<48, blk, 0, stream>>>(p1hat, Bqk, qtil, bq2, 1024, CC, CC, CC,
      nullptr);
  dotc_k<<<256, blk, 0, stream>>>(p1hat, wqb, cq, qdotv);

  // 5) enc attention: attn = relu(qtil@xhat^T + qdot)*scale; softmax(+attn_0);
  //    pv2 = sm@xhat (split-K); parts_in = pv2@(Wv'Wp) + bias2 + parts1
  gemm_k<2, true, 64, 128><<<dim3(16, 1, 16), blk, 0, stream>>>(
      qtil, bufA, attn_e, nullptr, 64, PP, CC, CC, CC,
      (long)64 * CC, (long)PP * CC, (long)64 * PP, scale, nullptr, qdotv);
  softmax_enc_k<<<256, blk, 0, stream>>>(attn_e, sm_e, outp + (long)BB * CC * PP);
  gemm_k<4, false, 64, 128><<<dim3(6, 4, 16), blk, 0, stream>>>(
      sm_e, bufA, pvpart, nullptr, 64, CC, PP / 4, PP, CC,
      (long)64 * PP, (long)PP * CC, (long)64 * CC, 0.f, nullptr, nullptr);
  pvred_k<<<768, blk, 0, stream>>>(pvpart, pv_e);
  gemmf_k<4><<<48, blk, 0, stream>>>(pv_e, m2w, parts_in, bias2, 1024, CC, CC, CC,
      parts1);

  // 6) dec combined operands from LN(parts_in): GVW = pin_hat@Bgv^T (+bias_gv)
  ln_rows_k<float><<<256, blk, 0, stream>>>(parts_in, pin_hat, 1024);
  gemmf_k<0><<<96, blk, 0, stream>>>(pin_hat, Bgv, GVW, bias_gv, 1024, 2 * CC, CC,
      CC, nullptr);
  dotc_k<<<256, blk, 0, stream>>>(pin_hat, wkb, ck, kdotv);

  // 7) FFN: feats1 = x + gelu(xhat@W1'+b1')@W2 + b2  -> bufB (both on gemm256)
  for (long r0 = 0; r0 < 32768; r0 += chunk_rows) {
    gemm256_k<1><<<(chunk_rows / 256) * 12, blk2, 0, stream>>>(
        bufA + r0 * CC, W1T, ff1, b1f, chunk_rows, FF, CC,
        nullptr, nullptr, nullptr, 0);
    gemm256_k<3><<<(chunk_rows / 256) * 3, blk2, 0, stream>>>(
        ff1, W2T, bufB + r0 * CC, ffn_b2, chunk_rows, CC, FF,
        bufA, meanx, rstdx, r0);
  }
  // 8) LN(feats1) in place
  ln_rows_k<u16><<<8192, blk, 0, stream>>>(bufB, bufB, 32768);

  // 9+10) fused dec attention: QK^T + softmax + PV + transposed residual
  decattn_k<<<dim3(16, 16), blk, 0, stream>>>(
      bufB, GVW, kdotv, x, dec_bp, outp, scale);
}

// Round 10
// 1002.973 us; speedup vs baseline: 1.0739x; 1.0160x over previous
//
#include <hip/hip_runtime.h>

typedef unsigned short u16;
typedef unsigned int u32;
typedef __bf16 bf16x8 __attribute__((ext_vector_type(8)));
typedef float f32x4 __attribute__((ext_vector_type(4)));
typedef unsigned int u32x4 __attribute__((ext_vector_type(4)));

#define BB 16
#define CC 768
#define PP 2048
#define FF 3072

__device__ __forceinline__ float b2f(u16 u) {
  unsigned int x = ((unsigned int)u) << 16;
  return __builtin_bit_cast(float, x);
}
__device__ __forceinline__ u16 f2b(float f) {
  unsigned int x = __builtin_bit_cast(unsigned int, f);
  x += 0x7fffu + ((x >> 16) & 1u);
  return (u16)(x >> 16);
}
// erf via Abramowitz-Stegun 7.1.26 (|err|<=1.5e-7; invisible after bf16 round)
__device__ __forceinline__ float erf_fast(float x) {
  float ax = fabsf(x);
  float t = 1.0f / fmaf(0.3275911f, ax, 1.0f);
  float p = t * fmaf(t, fmaf(t, fmaf(t, fmaf(t, 1.061405429f, -1.453152027f),
                                     1.421413741f), -0.284496736f), 0.254829592f);
  float r = 1.0f - p * __expf(-ax * ax);
  return copysignf(r, x);
}
__device__ __forceinline__ float gelu_f(float x) {
  return 0.5f * x * (1.0f + erf_fast(x * 0.7071067811865475f));
}

typedef __attribute__((address_space(1))) const unsigned int g_u32;
typedef __attribute__((address_space(3))) unsigned int l_u32;
__device__ __forceinline__ void gl_lds16(const u16* g, u16* l) {
  __builtin_amdgcn_global_load_lds((g_u32*)g, (l_u32*)l, 16, 0, 0);
}

// --------- fused weight prep: tr: Wt[n,k]=g[k]W[k,n] | copy: Wt[k,n]=g[k]W[k,n]
struct Wtr10 {
  const float* W[10]; const float* g[10]; u16* O[10];
  int Kd[10]; int Nd[10]; int tr[10]; int cum[11];
};
__global__ void wtr10_k(Wtr10 a) {
  __shared__ float t[64][65];
  int tbid = blockIdx.x;
  int z = 0;
  while (tbid >= a.cum[z + 1]) ++z;
  int r = tbid - a.cum[z];
  const float* W = a.W[z];
  const float* g = a.g[z];
  u16* Wt = a.O[z];
  int K = a.Kd[z], N = a.Nd[z];
  int nbx = N >> 6;
  int n0 = (r % nbx) * 64, k0 = (r / nbx) * 64;
  int tx = threadIdx.x & 63, ty = threadIdx.x >> 6;
  if (!a.tr[z]) {  // scaled copy, row-major [K][N]
    for (int i = 0; i < 16; ++i) {
      int k = k0 + ty + i * 4;
      float sc = g ? g[k] : 1.0f;
      Wt[(long)k * N + n0 + tx] = f2b(W[(long)k * N + n0 + tx] * sc);
    }
    return;
  }
  for (int i = 0; i < 16; ++i) {
    int k = k0 + ty + i * 4;
    float sc = g ? g[k] : 1.0f;
    t[ty + i * 4][tx] = W[(long)k * N + n0 + tx] * sc;
  }
  __syncthreads();
  for (int i = 0; i < 16; ++i) {
    int n = n0 + ty + i * 4;
    Wt[(long)n * K + k0 + tx] = f2b(t[tx][ty + i * 4]);
  }
}

// fused bias prep: b'[n] = b[n] + sum_k nb[k]*W[k,n]
struct Bf7 {
  const float* b[7]; const float* nb[7]; const float* W[7]; float* o[7];
  int Kd[7]; int Nd[7];
};
__global__ void bfuse7_k(Bf7 a) {
  __shared__ float red[4][64];
  int tbid = blockIdx.x;
  int z, bx;
  if (tbid < 72) { z = tbid / 12; bx = tbid % 12; }
  else { z = 6; bx = tbid - 72; }
  const float* b = a.b[z];
  const float* nb = a.nb[z];
  const float* W = a.W[z];
  float* outb = a.o[z];
  int K = a.Kd[z], N = a.Nd[z];
  int n = bx * 64 + (threadIdx.x & 63);
  int slice = threadIdx.x >> 6;
  float acc = 0.f;
#pragma unroll 4
  for (int k = slice; k < K; k += 4) acc += nb[k] * W[(long)k * N + n];
  red[slice][threadIdx.x & 63] = acc;
  __syncthreads();
  if (slice == 0)
    outb[n] = b[n] + red[0][threadIdx.x & 63] + red[1][threadIdx.x & 63] +
              red[2][threadIdx.x & 63] + red[3][threadIdx.x & 63];
}

// 2 batched bias fuses over [768][768] f32 weights + 2 scalar dots (block 24)
struct Bf2 {
  const float* b[2]; const float* nb[2]; const float* W[2]; float* o[2];
  const float* sa0; const float* sb0; float* so0;
  const float* sa1; const float* sb1; float* so1;
};
__global__ void bfuse2_k(Bf2 a) {
  if (blockIdx.x == 24) {
    if (threadIdx.x < 128) {
      int w = threadIdx.x >> 6, lane = threadIdx.x & 63;
      const float* A = w ? a.sa1 : a.sa0;
      const float* Bv = w ? a.sb1 : a.sb0;
      float s = 0.f;
      for (int i = lane; i < CC; i += 64) s += A[i] * Bv[i];
      for (int o = 32; o; o >>= 1) s += __shfl_xor(s, o);
      if (lane == 0) *(w ? a.so1 : a.so0) = s;
    }
    return;
  }
  __shared__ float red[4][64];
  int z = blockIdx.x / 12, bx = blockIdx.x % 12;
  const float* b = a.b[z];
  const float* nb = a.nb[z];
  const float* W = a.W[z];
  int n = bx * 64 + (threadIdx.x & 63);
  int slice = threadIdx.x >> 6;
  float acc = 0.f;
#pragma unroll 4
  for (int k = slice; k < CC; k += 4) acc += nb[k] * W[(long)k * CC + n];
  red[slice][threadIdx.x & 63] = acc;
  __syncthreads();
  if (slice == 0)
    a.o[z][n] = (b ? b[n] : 0.f) + red[0][threadIdx.x & 63] +
                red[1][threadIdx.x & 63] + red[2][threadIdx.x & 63] +
                red[3][threadIdx.x & 63];
}

// 4 batched weight-row dots: o[r] = bf16 A[r,:] . vec  (768 rows each)
struct Dw4 { const u16* A[4]; const float* v[4]; float* o[4]; };
__global__ void dotw4_k(Dw4 a) {
  int z = blockIdx.x / 192;
  int row = (blockIdx.x % 192) * 4 + (threadIdx.x >> 6);
  int lane = threadIdx.x & 63;
  const u16* ip = a.A[z] + (long)row * CC;
  const float* vec = a.v[z];
  float s = 0.f;
  for (int i = 0; i < 12; ++i) s += b2f(ip[lane + i * 64]) * vec[lane + i * 64];
  for (int o = 32; o; o >>= 1) s += __shfl_xor(s, o);
  if (lane == 0) a.o[z][row] = s;
}

// out[r] = bf16 A[r,:768] . vec + *cptr   (1024 rows)
__global__ void dotc_k(const u16* __restrict__ A, const float* __restrict__ vec,
                       const float* __restrict__ cptr, float* __restrict__ outp) {
  int row = blockIdx.x * 4 + (threadIdx.x >> 6);
  int lane = threadIdx.x & 63;
  const u16* ip = A + (long)row * CC;
  float s = 0.f;
  for (int i = 0; i < 12; ++i) s += b2f(ip[lane + i * 64]) * vec[lane + i * 64];
  for (int o = 32; o; o >>= 1) s += __shfl_xor(s, o);
  if (lane == 0) outp[row] = s + cptr[0];
}

// ------- fused x prep: stats over C + transposed xhat -------
__global__ void xprep_k(const float* __restrict__ x, float* __restrict__ mean,
                        float* __restrict__ rstd, u16* __restrict__ xh) {
  __shared__ float t[64][65];
  __shared__ float red[8][64];
  __shared__ float mn_s[64], rs_s[64];
  int p0 = blockIdx.x * 64, b = blockIdx.y;
  int tx = threadIdx.x & 63, ty = threadIdx.x >> 6;
  const float* xb = x + (long)b * CC * PP;
  float s = 0.f, sq = 0.f;
  for (int c = ty; c < CC; c += 4) {
    float f = xb[(long)c * PP + p0 + tx];
    s += f; sq += f * f;
  }
  red[ty][tx] = s;
  red[4 + ty][tx] = sq;
  __syncthreads();
  if (ty == 0) {
    float S = red[0][tx] + red[1][tx] + red[2][tx] + red[3][tx];
    float Q = red[4][tx] + red[5][tx] + red[6][tx] + red[7][tx];
    float m = S * (1.0f / 768.0f);
    float var = Q * (1.0f / 768.0f) - m * m;
    float rs = rsqrtf(var + 1e-5f);
    mn_s[tx] = m; rs_s[tx] = rs;
    int gi = (b << 11) + p0 + tx;
    mean[gi] = m; rstd[gi] = rs;
  }
  __syncthreads();
  u16* ob = xh + (long)b * PP * CC;
  for (int cb = 0; cb < 12; ++cb) {
    int c0 = cb * 64;
    for (int i = 0; i < 16; ++i)
      t[ty + i * 4][tx] = xb[(long)(c0 + ty + i * 4) * PP + p0 + tx];
    __syncthreads();
    for (int i = 0; i < 16; ++i) {
      int pl = ty + i * 4;
      ob[(long)(p0 + pl) * CC + c0 + tx] = f2b((t[tx][pl] - mn_s[pl]) * rs_s[pl]);
    }
    __syncthreads();
  }
}

// ---------------- SimpleReasoning gate (compute only) ----------------
__global__ void parts_gate_k(const float* __restrict__ parts,
                             const float* __restrict__ w1, const float* __restrict__ b1,
                             const float* __restrict__ w2, const float* __restrict__ b2,
                             float* __restrict__ gate_out) {
  int b = blockIdx.x, t = threadIdx.x;
  __shared__ float g[64], g1[64];
  int r = t >> 2, l4 = t & 3;
  const float* pr = parts + ((long)b * 64 + r) * CC;
  float m = -1e30f;
  for (int c = l4; c < CC; c += 4) m = fmaxf(m, pr[c]);
  m = fmaxf(m, __shfl_xor(m, 1));
  m = fmaxf(m, __shfl_xor(m, 2));
  if (l4 == 0) g[r] = m;
  __syncthreads();
  if (t < 64) {
    float a = b1[t];
    for (int k = 0; k < 64; ++k) a += g[k] * w1[k * 64 + t];
    g1[t] = gelu_f(a);
  }
  __syncthreads();
  if (t < 64) {
    float a = b2[t];
    for (int k = 0; k < 64; ++k) a += g1[k] * w2[k * 64 + t];
    gate_out[b * 64 + t] = 1.0f / (1.0f + expf(-a));
  }
}

// gate-apply + parts1 write + LN -> p1hat, one pass. 1024 rows.
__global__ void gate_ln_k(const float* __restrict__ parts, const float* __restrict__ gate,
                          float* __restrict__ parts1, u16* __restrict__ ph) {
  int row = blockIdx.x * 4 + (threadIdx.x >> 6);
  int lane = threadIdx.x & 63;
  float g = 1.0f + gate[row];
  const float* ip = parts + (long)row * CC;
  float* op1 = parts1 + (long)row * CC;
  float v[12];
  float s = 0.f, sq = 0.f;
  for (int i = 0; i < 12; ++i) {
    float f = ip[lane + i * 64] * g;
    v[i] = f; op1[lane + i * 64] = f;
    s += f; sq += f * f;
  }
  for (int o = 32; o; o >>= 1) { s += __shfl_xor(s, o); sq += __shfl_xor(sq, o); }
  float mean = s * (1.0f / 768.0f);
  float var = sq * (1.0f / 768.0f) - mean * mean;
  float rstd = rsqrtf(var + 1e-5f);
  u16* op = ph + (long)row * CC;
  for (int i = 0; i < 12; ++i) op[lane + i * 64] = f2b((v[i] - mean) * rstd);
}

// ---------------- LN rows (C=768), wave per row, bf16 out ----------------
template <typename T>
__global__ void ln_rows_k(const T* __restrict__ in, u16* __restrict__ outp, int rows) {
  int row = blockIdx.x * 4 + (threadIdx.x >> 6);
  if (row >= rows) return;
  int lane = threadIdx.x & 63;
  const T* ip = in + (long)row * CC;
  float v[12];
  float s = 0.f, sq = 0.f;
  for (int i = 0; i < 12; ++i) {
    float f;
    if constexpr (sizeof(T) == 2) f = b2f(((const u16*)ip)[lane + i * 64]);
    else f = ((const float*)ip)[lane + i * 64];
    v[i] = f; s += f; sq += f * f;
  }
  for (int o = 32; o; o >>= 1) { s += __shfl_xor(s, o); sq += __shfl_xor(sq, o); }
  float mean = s * (1.0f / 768.0f);
  float var = sq * (1.0f / 768.0f) - mean * mean;
  float rstd = rsqrtf(var + 1e-5f);
  u16* op = outp + (long)row * CC;
  for (int i = 0; i < 12; ++i) op[lane + i * 64] = f2b((v[i] - mean) * rstd);
}

// ---------------- enc softmax ----------------
__global__ void softmax_enc_k(const float* __restrict__ attn, u16* __restrict__ sm,
                              float* __restrict__ attn0) {
  int row = blockIdx.x * 4 + (threadIdx.x >> 6);
  int lane = threadIdx.x & 63;
  const float* ap = attn + (long)row * PP;
  float v[32];
  float m = -1e30f;
  for (int i = 0; i < 32; ++i) { v[i] = ap[lane + i * 64]; m = fmaxf(m, v[i]); }
  for (int o = 32; o; o >>= 1) m = fmaxf(m, __shfl_xor(m, o));
  float s = 0.f;
  for (int i = 0; i < 32; ++i) { float e = expf(v[i] - m); v[i] = e; s += e; }
  for (int o = 32; o; o >>= 1) s += __shfl_xor(s, o);
  float inv = 1.0f / s;
  u16* sp = sm + (long)row * PP;
  for (int i = 0; i < 32; ++i) sp[lane + i * 64] = f2b(v[i] * inv);
  if (lane == 0) attn0[row] = m;
}

// split-K reduce: pv_e = bf16(sum of 4 f32 partials)
__global__ void pvred_k(const float* __restrict__ part, u16* __restrict__ outp) {
  long i = (long)blockIdx.x * 256 + threadIdx.x;
  const f32x4* p = (const f32x4*)part;
  f32x4 a = p[i];
  a += p[i + 196608];
  a += p[i + 2 * 196608];
  a += p[i + 3 * 196608];
  u32 lo = (u32)f2b(a.x) | ((u32)f2b(a.y) << 16);
  u32 hi = (u32)f2b(a.z) | ((u32)f2b(a.w) << 16);
  ((u32*)outp)[i * 2] = lo;
  ((u32*)outp)[i * 2 + 1] = hi;
}

// ---------- FAST GEMM (m97): C = A[M,K](lda)*B[N,K]^T, M,N%128==0, K%32==0
// EPI: 0 bias?->bf16 | 4 bias+res32->f32
template <int EPI>
__global__ __launch_bounds__(256) void gemmf_k(
    const u16* __restrict__ A, const u16* __restrict__ Bm, void* __restrict__ Cm,
    const float* __restrict__ bias, int M, int N, int K, int lda,
    const float* __restrict__ res32) {
  __shared__ __align__(16) u16 As[128 * 32];
  __shared__ __align__(16) u16 Bs[128 * 32];
  const int nbx = N >> 7;
  const int nwg = gridDim.x;
  int tile = blockIdx.x;
  if ((nwg & 7) == 0) {
    tile = (tile & 7) * (nwg >> 3) + (tile >> 3);
  }
  const int bm0 = (tile / nbx) << 7;
  const int bn0 = (tile % nbx) << 7;
  const int tid = threadIdx.x;
  const int lane = tid & 63;
  const int wave = tid >> 6;
  const int laneq = lane & 15, lanek = lane >> 4;
  const int wm = (wave >> 1) << 6, wn = (wave & 1) << 6;
  const int srow = wave * 32 + (lane >> 2);
  const int scol = (lane & 3) << 3;
  const u16* Ag0 = A + (long)(bm0 + srow) * lda + scol;
  const u16* Ag1 = A + (long)(bm0 + srow + 16) * lda + scol;
  const u16* Bg0 = Bm + (long)(bn0 + srow) * K + scol;
  const u16* Bg1 = Bm + (long)(bn0 + srow + 16) * K + scol;
  u16* lA0 = As + wave * 1024;
  u16* lA1 = As + wave * 1024 + 512;
  u16* lB0 = Bs + wave * 1024;
  u16* lB1 = Bs + wave * 1024 + 512;
  f32x4 acc[4][4] = {};
  for (int k0 = 0; k0 < K; k0 += 32) {
    gl_lds16(Ag0 + k0, lA0);
    gl_lds16(Ag1 + k0, lA1);
    gl_lds16(Bg0 + k0, lB0);
    gl_lds16(Bg1 + k0, lB1);
    __syncthreads();
    bf16x8 af[4], bfr[4];
#pragma unroll
    for (int i = 0; i < 4; ++i)
      af[i] = *(const bf16x8*)(As + (wm + i * 16 + laneq) * 32 + (lanek << 3));
#pragma unroll
    for (int i = 0; i < 4; ++i)
      bfr[i] = *(const bf16x8*)(Bs + (wn + i * 16 + laneq) * 32 + (lanek << 3));
#pragma unroll
    for (int mi = 0; mi < 4; ++mi)
#pragma unroll
      for (int ni = 0; ni < 4; ++ni)
        acc[mi][ni] =
            __builtin_amdgcn_mfma_f32_16x16x32_bf16(af[mi], bfr[ni], acc[mi][ni], 0, 0, 0);
    __syncthreads();
  }
#pragma unroll
  for (int mi = 0; mi < 4; ++mi) {
#pragma unroll
    for (int r = 0; r < 4; ++r) {
      const int row = bm0 + wm + mi * 16 + (lanek << 2) + r;
#pragma unroll
      for (int ni = 0; ni < 4; ++ni) {
        const int col = bn0 + wn + ni * 16 + laneq;
        float v = acc[mi][ni][r] + (bias ? bias[col] : 0.f);
        long off = (long)row * N + col;
        if constexpr (EPI == 0) {
          ((u16*)Cm)[off] = f2b(v);
        } else {
          ((float*)Cm)[off] = v + res32[off];
        }
      }
    }
  }
}

// batched 4x 768^3 weight-product GEMM: C[z] = A[z]@B[z]^T (bf16 out, no bias)
struct G4 { const u16* A[4]; const u16* B[4]; u16* C[4]; };
__global__ __launch_bounds__(256) void gemmf4_k(G4 a) {
  __shared__ __align__(16) u16 As[128 * 32];
  __shared__ __align__(16) u16 Bs[128 * 32];
  const int z = blockIdx.x / 36;
  const int r = blockIdx.x % 36;
  const u16* A = a.A[z];
  const u16* Bm = a.B[z];
  u16* Cm = a.C[z];
  const int bm0 = (r / 6) << 7;
  const int bn0 = (r % 6) << 7;
  const int tid = threadIdx.x;
  const int lane = tid & 63;
  const int wave = tid >> 6;
  const int laneq = lane & 15, lanek = lane >> 4;
  const int wm = (wave >> 1) << 6, wn = (wave & 1) << 6;
  const int srow = wave * 32 + (lane >> 2);
  const int scol = (lane & 3) << 3;
  const u16* Ag0 = A + (long)(bm0 + srow) * CC + scol;
  const u16* Ag1 = A + (long)(bm0 + srow + 16) * CC + scol;
  const u16* Bg0 = Bm + (long)(bn0 + srow) * CC + scol;
  const u16* Bg1 = Bm + (long)(bn0 + srow + 16) * CC + scol;
  u16* lA0 = As + wave * 1024;
  u16* lA1 = As + wave * 1024 + 512;
  u16* lB0 = Bs + wave * 1024;
  u16* lB1 = Bs + wave * 1024 + 512;
  f32x4 acc[4][4] = {};
  for (int k0 = 0; k0 < CC; k0 += 32) {
    gl_lds16(Ag0 + k0, lA0);
    gl_lds16(Ag1 + k0, lA1);
    gl_lds16(Bg0 + k0, lB0);
    gl_lds16(Bg1 + k0, lB1);
    __syncthreads();
    bf16x8 af[4], bfr[4];
#pragma unroll
    for (int i = 0; i < 4; ++i)
      af[i] = *(const bf16x8*)(As + (wm + i * 16 + laneq) * 32 + (lanek << 3));
#pragma unroll
    for (int i = 0; i < 4; ++i)
      bfr[i] = *(const bf16x8*)(Bs + (wn + i * 16 + laneq) * 32 + (lanek << 3));
#pragma unroll
    for (int mi = 0; mi < 4; ++mi)
#pragma unroll
      for (int ni = 0; ni < 4; ++ni)
        acc[mi][ni] =
            __builtin_amdgcn_mfma_f32_16x16x32_bf16(af[mi], bfr[ni], acc[mi][ni], 0, 0, 0);
    __syncthreads();
  }
#pragma unroll
  for (int mi = 0; mi < 4; ++mi)
#pragma unroll
    for (int r2 = 0; r2 < 4; ++r2) {
      const int row = bm0 + wm + mi * 16 + (lanek << 2) + r2;
#pragma unroll
      for (int ni = 0; ni < 4; ++ni) {
        const int col = bn0 + wn + ni * 16 + laneq;
        Cm[(long)row * CC + col] = f2b(acc[mi][ni][r2]);
      }
    }
}

// ---------- 256x256 8-phase GEMM body: C = A[M,K]*B[N,K]^T (FFN) ---------
#define G256_BAR() __builtin_amdgcn_s_barrier()
#define G256_WLGKM0()                                    \
  do {                                                   \
    asm volatile("s_waitcnt lgkmcnt(0)" ::: "memory");   \
    __builtin_amdgcn_sched_barrier(0);                   \
  } while (0)
#define G256_RD_A(HALF)                                                        \
  _Pragma("unroll") for (int m2 = 0; m2 < 4; ++m2) {                           \
    af[m2 * 2 + 0] = *(const bf16x8*)(Ab + ar + (HALF)*4096 + m2 * 1024 + g0); \
    af[m2 * 2 + 1] = *(const bf16x8*)(Ab + ar + (HALF)*4096 + m2 * 1024 + g1); \
  }
#define G256_RD_B(HALF, BFR)                                                   \
  _Pragma("unroll") for (int n2 = 0; n2 < 2; ++n2) {                           \
    BFR[n2 * 2 + 0] = *(const bf16x8*)(Bb + br + (HALF)*2048 + n2 * 1024 + g0);\
    BFR[n2 * 2 + 1] = *(const bf16x8*)(Bb + br + (HALF)*2048 + n2 * 1024 + g1);\
  }
#define G256_MFMA_Q(H, NH, BFR)                                                \
  __builtin_amdgcn_s_setprio(1);                                               \
  _Pragma("unroll") for (int m2 = 0; m2 < 4; ++m2)                             \
  _Pragma("unroll") for (int n2 = 0; n2 < 2; ++n2)                             \
  _Pragma("unroll") for (int s = 0; s < 2; ++s)                                \
      acc[(H)*4 + m2][(NH)*2 + n2] = __builtin_amdgcn_mfma_f32_16x16x32_bf16(  \
          af[m2 * 2 + s], BFR[n2 * 2 + s], acc[(H)*4 + m2][(NH)*2 + n2], 0, 0, 0); \
  __builtin_amdgcn_s_setprio(0);

template <int EPI>
__device__ __forceinline__ void g256_body(
    u16* As, u16* Bs, int tileIn, int nwg,
    const u16* __restrict__ A, const u16* __restrict__ Bm, void* __restrict__ Cm,
    const float* __restrict__ bias, int M, int N, int K,
    const u16* __restrict__ rxh, const float* __restrict__ rmean,
    const float* __restrict__ rrstd, long rro) {
  const int nbx = N >> 8;
  int tile = tileIn;
  if ((nwg & 7) == 0) {
    tile = (tile & 7) * (nwg >> 3) + (tile >> 3);
  }
  const int bm0 = (tile / nbx) << 8;
  const int bn0 = (tile % nbx) << 8;
  const int tid = threadIdx.x;
  const int lane = tid & 63;
  const int wave = tid >> 6;
  const int laneq = lane & 15, lanek = lane >> 4;
  const int wrow = (wave >> 2) << 7;
  const int wcol = (wave & 3) << 6;
  const int srow8 = lane >> 3;
  const int sg = (lane & 7) ^ srow8;
  const u16* gA = A + (long)(bm0 + wave * 8 + srow8) * K + sg * 8;
  const u16* gB = Bm + (long)(bn0 + wave * 8 + srow8) * K + sg * 8;
  const long lineK = (long)64 * K;
  const int ldsLine = wave * 512;
  const int gx = laneq & 7;
  const int g0 = ((lanek) ^ gx) << 3;
  const int g1 = ((lanek + 4) ^ gx) << 3;
  const int ar = (wrow + laneq) * 64;
  const int br = (wcol + laneq) * 64;
  f32x4 acc[8][4] = {};
  bf16x8 af[8], bfr0[4], bfr1[4];
  const int NT = K >> 6;

  {
    u16* dA = As;
    u16* dB = Bs;
    gl_lds16(gA, dA + ldsLine);
    gl_lds16(gA + lineK, dA + ldsLine + 4096);
    gl_lds16(gA + 2 * lineK, dA + ldsLine + 8192);
    gl_lds16(gA + 3 * lineK, dA + ldsLine + 12288);
    gl_lds16(gB, dB + ldsLine);
    gl_lds16(gB + lineK, dB + ldsLine + 4096);
    gl_lds16(gB + 2 * lineK, dB + ldsLine + 8192);
    gl_lds16(gB + 3 * lineK, dB + ldsLine + 12288);
  }
  for (int T = 0; T < NT; ++T) {
    const u16* Ab = As + (T & 1) * 16384;
    const u16* Bb = Bs + (T & 1) * 16384;
    u16* An = As + ((T & 1) ^ 1) * 16384;
    u16* Bn = Bs + ((T & 1) ^ 1) * 16384;
    const long ko = (long)(T + 1) * 64;
    const bool more = (T + 1 < NT);
    if (more) {
      gl_lds16(gA + ko, An + ldsLine);
      gl_lds16(gA + ko + lineK, An + ldsLine + 4096);
      gl_lds16(gB + ko, Bn + ldsLine);
      gl_lds16(gB + ko + lineK, Bn + ldsLine + 4096);
      asm volatile("s_waitcnt vmcnt(4)" ::: "memory");
    } else {
      asm volatile("s_waitcnt vmcnt(0)" ::: "memory");
    }
    G256_BAR();
    G256_RD_A(0);
    G256_RD_B(0, bfr0);
    G256_WLGKM0();
    G256_MFMA_Q(0, 0, bfr0);
    G256_BAR();
    if (more) {
      gl_lds16(gA + ko + 2 * lineK, An + ldsLine + 8192);
      gl_lds16(gA + ko + 3 * lineK, An + ldsLine + 12288);
      gl_lds16(gB + ko + 2 * lineK, Bn + ldsLine + 8192);
      gl_lds16(gB + ko + 3 * lineK, Bn + ldsLine + 12288);
    }
    G256_RD_B(1, bfr1);
    G256_BAR();
    G256_WLGKM0();
    G256_MFMA_Q(0, 1, bfr1);
    G256_BAR();
    G256_RD_A(1);
    G256_BAR();
    G256_WLGKM0();
    G256_MFMA_Q(1, 1, bfr1);
    G256_BAR();
    G256_MFMA_Q(1, 0, bfr0);
  }

#pragma unroll
  for (int mi = 0; mi < 8; ++mi) {
#pragma unroll
    for (int r = 0; r < 4; ++r) {
      const int row = bm0 + wrow + mi * 16 + (lanek << 2) + r;
      float mn = 0.f, istd = 0.f;
      if constexpr (EPI == 3) {
        long gr = rro + row;
        mn = rmean[gr];
        istd = 1.0f / rrstd[gr];
      }
#pragma unroll
      for (int ni = 0; ni < 4; ++ni) {
        const int col = bn0 + wcol + ni * 16 + laneq;
        float v = acc[mi][ni][r] + bias[col];
        long off = (long)row * N + col;
        if constexpr (EPI == 0) {
          ((u16*)Cm)[off] = f2b(v);
        } else if constexpr (EPI == 1) {
          ((u16*)Cm)[off] = f2b(gelu_f(v));
        } else {
          v += b2f(rxh[(rro + row) * 768 + col]) * istd + mn;
          ((u16*)Cm)[off] = f2b(v);
        }
      }
    }
  }
}

template <int EPI>
__global__ __launch_bounds__(512, 2) void gemm256_k(
    const u16* __restrict__ A, const u16* __restrict__ Bm, void* __restrict__ Cm,
    const float* __restrict__ bias, int M, int N, int K,
    const u16* __restrict__ rxh, const float* __restrict__ rmean,
    const float* __restrict__ rrstd, long rro) {
  __shared__ __align__(16) u16 As[2 * 16384];
  __shared__ __align__(16) u16 Bs[2 * 16384];
  g256_body<EPI>(As, Bs, blockIdx.x, gridDim.x, A, Bm, Cm, bias, M, N, K,
                 rxh, rmean, rrstd, rro);
}

// mixed FFN dispatch: blocks [0,192) = down-proj of chunk1 (long blocks, NT=48),
// blocks [192,960) = up-proj of chunk2 (short blocks, NT=12). Down blocks are
// dispatched first so up blocks backfill the 64 CUs the down round leaves idle.
__global__ __launch_bounds__(512, 2) void ffn_mix_k(
    const u16* __restrict__ ff1a, const u16* __restrict__ W2T,
    u16* __restrict__ outDn, const float* __restrict__ b2,
    const u16* __restrict__ xh2, const u16* __restrict__ W1T,
    u16* __restrict__ ff1b, const float* __restrict__ b1f,
    const u16* __restrict__ rxh, const float* __restrict__ rmean,
    const float* __restrict__ rrstd) {
  __shared__ __align__(16) u16 As[2 * 16384];
  __shared__ __align__(16) u16 Bs[2 * 16384];
  if ((int)blockIdx.x < 192) {
    g256_body<3>(As, Bs, blockIdx.x, 192, ff1a, W2T, outDn, b2,
                 16384, CC, FF, rxh, rmean, rrstd, 0);
  } else {
    g256_body<1>(As, Bs, blockIdx.x - 192, 768, xh2, W1T, ff1b, b1f,
                 16384, FF, CC, nullptr, nullptr, nullptr, 0);
  }
}

// ---------------- GEMM (general/batched path, enc attention) ----------------
// BNT=true : B is [N,K] rows stride ldB. BNT=false: B is [K,N], k-stride ldB.
// EPI: 2 relu(acc+radd[bz*M+row])*scale->f32 | 4 raw f32 split-K
template <int EPI, bool BNT, int TM, int TN>
__global__ __launch_bounds__(256) void gemm_k(
    const u16* __restrict__ A, const u16* __restrict__ Bm, void* __restrict__ Cm,
    const float* __restrict__ bias, int M, int N, int kLen, int lda, int ldB,
    long sA, long sB, long sC, float scale, const float* __restrict__ res32,
    const float* __restrict__ radd) {
  __shared__ __align__(16) u16 As[TM][40];
  __shared__ __align__(16) u16 Bs[TN][40];
  const int bn0 = blockIdx.x * TN;
  const int bm0 = (EPI == 4) ? 0 : blockIdx.y * TM;
  const int kOff = (EPI == 4) ? blockIdx.y * kLen : 0;
  const int bz = blockIdx.z;
  const u16* Ab = A + (long)bz * sA;
  const u16* Bb = Bm + (long)bz * sB;
  const long coff = (EPI == 4) ? ((long)blockIdx.y * gridDim.z + bz) * sC
                               : (long)bz * sC;
  const int tid = threadIdx.x;
  const int lane = tid & 63;
  const int wave = tid >> 6;
  const int wm = (TM == 64) ? 0 : ((TN == 64) ? wave * 32 : ((wave >> 1) << 6));
  const int wn = (TN == 64) ? 0 : ((TM == 64) ? wave * 32 : ((wave & 1) << 6));
  constexpr int MI = (TN == 64) ? 2 : 4;
  constexpr int NI = (TM == 64) ? 2 : 4;
  const int laneq = lane & 15, lanek = lane >> 4;
  f32x4 acc[MI][NI] = {};
  for (int k0 = 0; k0 < kLen; k0 += 32) {
    __syncthreads();
#pragma unroll
    for (int j = 0; j < TM / 64; ++j) {
      int v = tid + j * 256;
      int m = v >> 2, kcl = (v & 3) << 3;
      u32x4 val = {0, 0, 0, 0};
      if (bm0 + m < M)
        val = *(const u32x4*)(Ab + (long)(bm0 + m) * lda + kOff + k0 + kcl);
      *(u32x4*)(&As[m][kcl]) = val;
    }
    if constexpr (BNT) {
#pragma unroll
      for (int j = 0; j < TN / 64; ++j) {
        int v = tid + j * 256;
        int n = v >> 2, kcl = (v & 3) << 3;
        u32x4 val = {0, 0, 0, 0};
        if (bn0 + n < N)
          val = *(const u32x4*)(Bb + (long)(bn0 + n) * ldB + kOff + k0 + kcl);
        *(u32x4*)(&Bs[n][kcl]) = val;
      }
    } else {
      constexpr int CCH = TN / 8;
#pragma unroll
      for (int j = 0; j < TN / 64; ++j) {
        int v = tid + j * 256;
        int kk = v / CCH, nc = (v % CCH) << 3;
        u32x4 val = {0, 0, 0, 0};
        if (bn0 + nc < N)
          val = *(const u32x4*)(Bb + (long)(kOff + k0 + kk) * ldB + bn0 + nc);
        union { u32x4 v4; u16 u[8]; } uu;
        uu.v4 = val;
#pragma unroll
        for (int e = 0; e < 8; ++e) Bs[nc + e][kk] = uu.u[e];
      }
    }
    __syncthreads();
    bf16x8 af[MI], bfr[NI];
#pragma unroll
    for (int i = 0; i < MI; ++i)
      af[i] = *(const bf16x8*)(&As[wm + i * 16 + laneq][lanek << 3]);
#pragma unroll
    for (int i = 0; i < NI; ++i)
      bfr[i] = *(const bf16x8*)(&Bs[wn + i * 16 + laneq][lanek << 3]);
#pragma unroll
    for (int mi = 0; mi < MI; ++mi)
#pragma unroll
      for (int ni = 0; ni < NI; ++ni)
        acc[mi][ni] =
            __builtin_amdgcn_mfma_f32_16x16x32_bf16(af[mi], bfr[ni], acc[mi][ni], 0, 0, 0);
  }
#pragma unroll
  for (int mi = 0; mi < MI; ++mi) {
#pragma unroll
    for (int ni = 0; ni < NI; ++ni) {
      int col = bn0 + wn + ni * 16 + laneq;
      if (col >= N) continue;
#pragma unroll
      for (int r = 0; r < 4; ++r) {
        int row = bm0 + wm + mi * 16 + (lanek << 2) + r;
        if (row >= M) continue;
        float v = acc[mi][ni][r];
        long off = coff + (long)row * N + col;
        if constexpr (EPI == 2) {
          v += radd ? radd[(long)bz * M + row] : 0.f;
          ((float*)Cm)[off] = fmaxf(v, 0.0f) * scale;
        } else {
          ((float*)Cm)[off] = v;
        }
      }
    }
  }
}

// ---------- fully fused dec attention: QK^T + softmax + PV + residual -------
__global__ __launch_bounds__(256) void decattn_k(
    const u16* __restrict__ fh, const u16* __restrict__ GVW,
    const float* __restrict__ kdotv, const float* __restrict__ x,
    const float* __restrict__ bias, float* __restrict__ outp, float scale) {
  __shared__ __align__(16) u16 As[128][40];
  __shared__ __align__(16) u16 Bs[64][40];
  __shared__ __align__(16) u16 Vs[768][68];   // VW transposed: Vs[c][j]
  __shared__ __align__(16) u16 Ps[128][72];   // P bf16
  __shared__ float Ts[4][1024];               // per-wave transpose scratch
  const int bm0 = blockIdx.x * 128;
  const int bz = blockIdx.y;
  const int tid = threadIdx.x, lane = tid & 63, wave = tid >> 6;
  const int laneq = lane & 15, lanek = lane >> 4;
  {
    const u16* vw = GVW + ((long)bz * 64) * 1536 + 768;
    for (int it = 0; it < 24; ++it) {
      int l8 = tid + it * 256;
      int j = l8 / 96;
      int c8 = (l8 % 96) * 8;
      union { bf16x8 v; u16 u[8]; } uu;
      uu.v = *(const bf16x8*)(vw + (long)j * 1536 + c8);
#pragma unroll
      for (int e = 0; e < 8; ++e) Vs[c8 + e][j] = uu.u[e];
    }
  }
  const u16* Ab = fh + (long)bz * PP * CC;
  const u16* Bb = GVW + (long)bz * 64 * 1536;
  const int wm = wave * 32;
  f32x4 acc[2][4] = {};
  for (int k0 = 0; k0 < CC; k0 += 32) {
    __syncthreads();
#pragma unroll
    for (int j = 0; j < 2; ++j) {
      int v = tid + j * 256;
      int m = v >> 2, kcl = (v & 3) << 3;
      *(u32x4*)(&As[m][kcl]) =
          *(const u32x4*)(Ab + (long)(bm0 + m) * CC + k0 + kcl);
    }
    {
      int n = tid >> 2, kcl = (tid & 3) << 3;
      *(u32x4*)(&Bs[n][kcl]) = *(const u32x4*)(Bb + (long)n * 1536 + k0 + kcl);
    }
    __syncthreads();
    bf16x8 af[2], bfr[4];
#pragma unroll
    for (int i = 0; i < 2; ++i)
      af[i] = *(const bf16x8*)(&As[wm + i * 16 + laneq][lanek << 3]);
#pragma unroll
    for (int i = 0; i < 4; ++i)
      bfr[i] = *(const bf16x8*)(&Bs[i * 16 + laneq][lanek << 3]);
#pragma unroll
    for (int mi = 0; mi < 2; ++mi)
#pragma unroll
      for (int ni = 0; ni < 4; ++ni)
        acc[mi][ni] =
            __builtin_amdgcn_mfma_f32_16x16x32_bf16(af[mi], bfr[ni], acc[mi][ni], 0, 0, 0);
  }
#pragma unroll
  for (int mi = 0; mi < 2; ++mi) {
#pragma unroll
    for (int r = 0; r < 4; ++r) {
      float e[4];
      float mx = -1e30f;
#pragma unroll
      for (int ni = 0; ni < 4; ++ni) {
        const int col = ni * 16 + laneq;
        float v = acc[mi][ni][r] + kdotv[(long)bz * 64 + col];
        v = fmaxf(v, 0.0f) * scale;
        e[ni] = v;
        mx = fmaxf(mx, v);
      }
      mx = fmaxf(mx, __shfl_xor(mx, 1));
      mx = fmaxf(mx, __shfl_xor(mx, 2));
      mx = fmaxf(mx, __shfl_xor(mx, 4));
      mx = fmaxf(mx, __shfl_xor(mx, 8));
      float s = 0.f;
#pragma unroll
      for (int ni = 0; ni < 4; ++ni) { e[ni] = __expf(e[ni] - mx); s += e[ni]; }
      s += __shfl_xor(s, 1);
      s += __shfl_xor(s, 2);
      s += __shfl_xor(s, 4);
      s += __shfl_xor(s, 8);
      float inv = 1.0f / s;
      const int prow = wm + mi * 16 + (lanek << 2) + r;
#pragma unroll
      for (int ni = 0; ni < 4; ++ni)
        Ps[prow][ni * 16 + laneq] = f2b(e[ni] * inv);
    }
  }
  __syncthreads();
  const int wr = (wave & 1) << 6;
  const int wc = (wave >> 1) << 6;
  const long obase = (long)bz * CC * PP;
  const int pbase = bm0 + wr + (lane & 3) * 16;
  for (int nc = 0; nc < 6; ++nc) {
    f32x4 a2[4][4] = {};
#pragma unroll
    for (int ks = 0; ks < 2; ++ks) {
      bf16x8 af[4], bfr[4];
#pragma unroll
      for (int i = 0; i < 4; ++i)
        af[i] = *(const bf16x8*)(&Ps[wr + i * 16 + laneq][ks * 32 + (lanek << 3)]);
#pragma unroll
      for (int i = 0; i < 4; ++i)
        bfr[i] = *(const bf16x8*)(&Vs[nc * 128 + wc + i * 16 + laneq]
                                     [ks * 32 + (lanek << 3)]);
#pragma unroll
      for (int mi = 0; mi < 4; ++mi)
#pragma unroll
        for (int ni = 0; ni < 4; ++ni)
          a2[mi][ni] =
              __builtin_amdgcn_mfma_f32_16x16x32_bf16(af[mi], bfr[ni], a2[mi][ni], 0, 0, 0);
    }
    float* smem = Ts[wave];
#pragma unroll
    for (int ni = 0; ni < 4; ++ni) {
#pragma unroll
      for (int mi = 0; mi < 4; ++mi)
#pragma unroll
        for (int r = 0; r < 4; ++r) {
          const int col = nc * 128 + wc + ni * 16 + laneq;
          smem[(mi * 16 + (lanek << 2) + r) * 16 + laneq] =
              a2[mi][ni][r] + bias[col];
        }
      const int c = nc * 128 + wc + ni * 16 + (lane >> 2);
      const float* xs = x + obase + (long)c * PP + pbase;
      float* os = outp + obase + (long)c * PP + pbase;
      const float* sr = smem + (lane & 3) * 256 + (lane >> 2);
#pragma unroll
      for (int q4 = 0; q4 < 4; ++q4) {
        f32x4 xv = *(const f32x4*)(xs + q4 * 4);
        f32x4 ov;
        ov.x = sr[(q4 * 4 + 0) * 16] + xv.x;
        ov.y = sr[(q4 * 4 + 1) * 16] + xv.y;
        ov.z = sr[(q4 * 4 + 2) * 16] + xv.z;
        ov.w = sr[(q4 * 4 + 3) * 16] + xv.w;
        *(f32x4*)(os + q4 * 4) = ov;
      }
    }
  }
}

extern "C" void kernel_launch(void* const* d_in, const int* in_sizes, int n_in,
                              void* d_out, int out_size, void* d_ws, size_t ws_size,
                              hipStream_t stream) {
  (void)in_sizes; (void)n_in; (void)out_size;
  const float* x        = (const float*)d_in[0];
  const float* parts    = (const float*)d_in[1];
  const float* enc_nq_g = (const float*)d_in[2];
  const float* enc_nq_b = (const float*)d_in[3];
  const float* enc_nk_g = (const float*)d_in[4];
  const float* enc_nk_b = (const float*)d_in[5];
  const float* enc_nv_g = (const float*)d_in[6];
  const float* enc_nv_b = (const float*)d_in[7];
  const float* enc_wq   = (const float*)d_in[8];
  const float* enc_wk   = (const float*)d_in[9];
  const float* enc_wv   = (const float*)d_in[10];
  const float* enc_wp   = (const float*)d_in[11];
  const float* enc_bq   = (const float*)d_in[12];
  const float* enc_bk   = (const float*)d_in[13];
  const float* enc_bv   = (const float*)d_in[14];
  const float* enc_bp   = (const float*)d_in[15];
  const float* dec_nq_g = (const float*)d_in[16];
  const float* dec_nq_b = (const float*)d_in[17];
  const float* dec_nk_g = (const float*)d_in[18];
  const float* dec_nk_b = (const float*)d_in[19];
  const float* dec_nv_g = (const float*)d_in[20];
  const float* dec_nv_b = (const float*)d_in[21];
  const float* dec_wq   = (const float*)d_in[22];
  const float* dec_wk   = (const float*)d_in[23];
  const float* dec_wv   = (const float*)d_in[24];
  const float* dec_wp   = (const float*)d_in[25];
  const float* dec_bq   = (const float*)d_in[26];
  const float* dec_bk   = (const float*)d_in[27];
  const float* dec_bv   = (const float*)d_in[28];
  const float* dec_bp   = (const float*)d_in[29];
  const float* ffn_ng   = (const float*)d_in[30];
  const float* ffn_nb   = (const float*)d_in[31];
  const float* ffn_w1   = (const float*)d_in[32];
  const float* ffn_b1   = (const float*)d_in[33];
  const float* ffn_w2   = (const float*)d_in[34];
  const float* ffn_b2   = (const float*)d_in[35];
  const float* sr_w1    = (const float*)d_in[36];
  const float* sr_b1    = (const float*)d_in[37];
  const float* sr_w2    = (const float*)d_in[38];
  const float* sr_b2    = (const float*)d_in[39];
  float* outp = (float*)d_out;

  char* base = (char*)d_ws;
  size_t used = 0;
  auto alloc = [&](size_t bytes) -> void* {
    void* p = base + used;
    used += (bytes + 255) & ~(size_t)255;
    return p;
  };
  const long MC = (long)CC * CC;
  u16* WpeT = (u16*)alloc(MC * 2);
  u16* WpdT = (u16*)alloc(MC * 2);
  u16* W1T  = (u16*)alloc((long)CC * FF * 2);
  u16* W2T  = (u16*)alloc((long)CC * FF * 2);
  u16* WkR  = (u16*)alloc(MC * 2);   // scaled copies (row = input dim)
  u16* WqR  = (u16*)alloc(MC * 2);
  u16* WvS  = (u16*)alloc(MC * 2);
  u16* WqdR = (u16*)alloc(MC * 2);
  u16* WkdR = (u16*)alloc(MC * 2);
  u16* WvdR = (u16*)alloc(MC * 2);
  u16* m2w  = (u16*)alloc(MC * 2);   // (Wv' Wp_enc) for pv-out
  u16* Bqk  = (u16*)alloc(MC * 2);   // enc q->score combined weight
  u16* Bgv  = (u16*)alloc(MC * 2 * 2);  // dec combined weights: Bg rows | Bv rows
  float* bqe  = (float*)alloc(CC * 4);
  float* bke  = (float*)alloc(CC * 4);
  float* bve  = (float*)alloc(CC * 4);
  float* bqd  = (float*)alloc(CC * 4);
  float* bkd  = (float*)alloc(CC * 4);
  float* bvd  = (float*)alloc(CC * 4);
  float* b1f  = (float*)alloc(FF * 4);
  float* bias2   = (float*)alloc(CC * 4);
  float* bias_gv = (float*)alloc(2 * CC * 4);   // bias_g | bias_vw
  float* bq2     = (float*)alloc(CC * 4);
  float* wqb     = (float*)alloc(CC * 4);
  float* wkb     = (float*)alloc(CC * 4);
  float* cq      = (float*)alloc(256);
  float* ck      = (float*)alloc(256);
  float* meanx = (float*)alloc((long)BB * PP * 4);
  float* rstdx = (float*)alloc((long)BB * PP * 4);
  const long BPC = (long)BB * PP * CC;
  u16* bufA = (u16*)alloc(BPC * 2);          // xhat
  u16* bufB = (u16*)alloc(BPC * 2);          // feats1 -> f1hat
  const long PC = (long)BB * 64 * CC;
  float* parts1   = (float*)alloc(PC * 4);
  float* gateb    = (float*)alloc((long)BB * 64 * 4);
  u16*   p1hat    = (u16*)alloc(PC * 2);
  u16*   qtil     = (u16*)alloc(PC * 2);
  float* qdotv    = (float*)alloc((long)BB * 64 * 4);
  float* attn_e   = (float*)alloc((long)BB * 64 * PP * 4);
  u16*   sm_e     = (u16*)alloc((long)BB * 64 * PP * 2);
  u16*   pv_e     = (u16*)alloc(PC * 2);
  float* pvpart   = (float*)alloc((long)4 * PC * 4);
  float* parts_in = (float*)alloc(PC * 4);
  u16*   pin_hat  = (u16*)alloc(PC * 2);
  u16*   GVW      = (u16*)alloc(PC * 2 * 2); // interleaved [1024][1536]: G | VW
  float* kdotv    = (float*)alloc((long)BB * 64 * 4);
  int chunk_rows = 16384;
  while (chunk_rows > 4096 &&
         used + (size_t)chunk_rows * FF * 2 > ws_size)
    chunk_rows >>= 1;
  u16* ff1a = (u16*)alloc((long)chunk_rows * FF * 2);
  bool dual = (chunk_rows == 16384) &&
              (used + (size_t)chunk_rows * FF * 2 <= ws_size);
  u16* ff1b = nullptr;
  if (dual) ff1b = (u16*)alloc((long)chunk_rows * FF * 2);
  if (used > ws_size) return;

  const float scale = 0.03608439182435161f;  // 768^-0.5
  dim3 blk(256);
  dim3 blk2(512);

  // 1) weight prep
  {
    Wtr10 wa;
    const float* Ws[10] = {enc_wp, dec_wp, ffn_w1, ffn_w2, enc_wk,
                           enc_wq, enc_wv, dec_wq, dec_wk, dec_wv};
    const float* gs[10] = {nullptr, nullptr, ffn_ng, nullptr, enc_nk_g,
                           enc_nq_g, enc_nv_g, dec_nq_g, dec_nk_g, dec_nv_g};
    u16* Os[10] = {WpeT, WpdT, W1T, W2T, WkR, WqR, WvS, WqdR, WkdR, WvdR};
    int Ks[10] = {CC, CC, CC, FF, CC, CC, CC, CC, CC, CC};
    int Ns[10] = {CC, CC, FF, CC, CC, CC, CC, CC, CC, CC};
    int tr[10] = {1, 1, 1, 1, 0, 0, 0, 0, 0, 0};
    int cum = 0;
    for (int i = 0; i < 10; ++i) {
      wa.W[i] = Ws[i]; wa.g[i] = gs[i]; wa.O[i] = Os[i];
      wa.Kd[i] = Ks[i]; wa.Nd[i] = Ns[i]; wa.tr[i] = tr[i];
      wa.cum[i] = cum;
      cum += (Ns[i] / 64) * (Ks[i] / 64);
    }
    wa.cum[10] = cum;
    wtr10_k<<<cum, blk, 0, stream>>>(wa);
    Bf7 ba;
    const float* bs[7] = {enc_bq, enc_bk, enc_bv, dec_bq, dec_bk, dec_bv, ffn_b1};
    const float* nbs[7] = {enc_nq_b, enc_nk_b, enc_nv_b, dec_nq_b, dec_nk_b,
                           dec_nv_b, ffn_nb};
    const float* ws[7] = {enc_wq, enc_wk, enc_wv, dec_wq, dec_wk, dec_wv, ffn_w1};
    float* os[7] = {bqe, bke, bve, bqd, bkd, bvd, b1f};
    for (int i = 0; i < 7; ++i) {
      ba.b[i] = bs[i]; ba.nb[i] = nbs[i]; ba.W[i] = ws[i]; ba.o[i] = os[i];
      ba.Kd[i] = CC; ba.Nd[i] = (i == 6) ? FF : CC;
    }
    bfuse7_k<<<120, blk, 0, stream>>>(ba);
    Bf2 b2a;
    b2a.b[0] = enc_bp;  b2a.nb[0] = bve; b2a.W[0] = enc_wp; b2a.o[0] = bias2;
    b2a.b[1] = nullptr; b2a.nb[1] = bvd; b2a.W[1] = dec_wp; b2a.o[1] = bias_gv + CC;
    b2a.sa0 = bqe; b2a.sb0 = bke; b2a.so0 = cq;
    b2a.sa1 = bkd; b2a.sb1 = bqd; b2a.so1 = ck;
    bfuse2_k<<<25, blk, 0, stream>>>(b2a);
    Dw4 da;
    da.A[0] = WkR;  da.v[0] = bqe; da.o[0] = bq2;      // bq2[c]=WkR[c,:].bqe
    da.A[1] = WqR;  da.v[1] = bke; da.o[1] = wqb;      // wqb[d]=WqR[d,:].bke
    da.A[2] = WqdR; da.v[2] = bkd; da.o[2] = bias_gv;  // bias_g[c]=WqdR[c,:].bkd
    da.A[3] = WkdR; da.v[3] = bqd; da.o[3] = wkb;      // wkb[d]=WkdR[d,:].bqd
    dotw4_k<<<768, blk, 0, stream>>>(da);
    G4 ga;
    ga.A[0] = WpeT; ga.B[0] = WvS;  ga.C[0] = m2w;
    ga.A[1] = WkR;  ga.B[1] = WqR;  ga.C[1] = Bqk;       // Bqk[c,d]=WkR[c,:].WqR[d,:]
    ga.A[2] = WqdR; ga.B[2] = WkdR; ga.C[2] = Bgv;       // Bg[c,d]=WqdR[c,:].WkdR[d,:]
    ga.A[3] = WpdT; ga.B[3] = WvdR; ga.C[3] = Bgv + MC;  // Bv[n,d]=WpdT[n,:].WvdR[d,:]
    gemmf4_k<<<144, blk, 0, stream>>>(ga);
  }

  // 2) x LN stats + xhat transpose (single fused pass)
  xprep_k<<<dim3(32, 16), blk, 0, stream>>>(x, meanx, rstdx, bufA);

  // 3) SimpleReasoning gate; gate-apply + LN fused
  parts_gate_k<<<16, blk, 0, stream>>>(parts, sr_w1, sr_b1, sr_w2, sr_b2, gateb);
  gate_ln_k<<<256, blk, 0, stream>>>(parts, gateb, parts1, p1hat);

  // 4) enc score operand: qtil = p1hat@Bqk^T + bq2; qdot = p1hat.wqb + cq
  gemmf_k<0><<<48, blk, 0, stream>>>(p1hat, Bqk, qtil, bq2, 1024, CC, CC, CC,
      nullptr);
  dotc_k<<<256, blk, 0, stream>>>(p1hat, wqb, cq, qdotv);

  // 5) enc attention: attn = relu(qtil@xhat^T + qdot)*scale; softmax(+attn_0);
  //    pv2 = sm@xhat (split-K); parts_in = pv2@(Wv'Wp) + bias2 + parts1
  gemm_k<2, true, 64, 128><<<dim3(16, 1, 16), blk, 0, stream>>>(
      qtil, bufA, attn_e, nullptr, 64, PP, CC, CC, CC,
      (long)64 * CC, (long)PP * CC, (long)64 * PP, scale, nullptr, qdotv);
  softmax_enc_k<<<256, blk, 0, stream>>>(attn_e, sm_e, outp + (long)BB * CC * PP);
  gemm_k<4, false, 64, 128><<<dim3(6, 4, 16), blk, 0, stream>>>(
      sm_e, bufA, pvpart, nullptr, 64, CC, PP / 4, PP, CC,
      (long)64 * PP, (long)PP * CC, (long)64 * CC, 0.f, nullptr, nullptr);
  pvred_k<<<768, blk, 0, stream>>>(pvpart, pv_e);
  gemmf_k<4><<<48, blk, 0, stream>>>(pv_e, m2w, parts_in, bias2, 1024, CC, CC, CC,
      parts1);

  // 6) dec combined operands from LN(parts_in): GVW = pin_hat@Bgv^T (+bias_gv)
  ln_rows_k<float><<<256, blk, 0, stream>>>(parts_in, pin_hat, 1024);
  gemmf_k<0><<<96, blk, 0, stream>>>(pin_hat, Bgv, GVW, bias_gv, 1024, 2 * CC, CC,
      CC, nullptr);
  dotc_k<<<256, blk, 0, stream>>>(pin_hat, wkb, ck, kdotv);

  // 7) FFN: feats1 = x + gelu(xhat@W1'+b1')@W2 + b2  -> bufB.
  //    dual: up(c1) -> [down(c1) + up(c2) mixed] -> down(c2); the mixed
  //    dispatch backfills down's 25%-idle round with up(c2) blocks.
  if (dual) {
    gemm256_k<1><<<768, blk2, 0, stream>>>(bufA, W1T, ff1a, b1f, 16384, FF, CC,
        nullptr, nullptr, nullptr, 0);
    ffn_mix_k<<<960, blk2, 0, stream>>>(ff1a, W2T, bufB, ffn_b2,
        bufA + (long)16384 * CC, W1T, ff1b, b1f, bufA, meanx, rstdx);
    gemm256_k<3><<<192, blk2, 0, stream>>>(ff1b, W2T, bufB + (long)16384 * CC,
        ffn_b2, 16384, CC, FF, bufA, meanx, rstdx, 16384);
  } else {
    for (long r0 = 0; r0 < 32768; r0 += chunk_rows) {
      gemm256_k<1><<<(chunk_rows / 256) * 12, blk2, 0, stream>>>(
          bufA + r0 * CC, W1T, ff1a, b1f, chunk_rows, FF, CC,
          nullptr, nullptr, nullptr, 0);
      gemm256_k<3><<<(chunk_rows / 256) * 3, blk2, 0, stream>>>(
          ff1a, W2T, bufB + r0 * CC, ffn_b2, chunk_rows, CC, FF,
          bufA, meanx, rstdx, r0);
    }
  }
  // 8) LN(feats1) in place
  ln_rows_k<u16><<<8192, blk, 0, stream>>>(bufB, bufB, 32768);

  // 9+10) fused dec attention: QK^T + softmax + PV + transposed residual
  decattn_k<<<dim3(16, 16), blk, 0, stream>>>(
      bufB, GVW, kdotv, x, dec_bp, outp, scale);
}